// Round 14
// baseline (1055.564 us; speedup 1.0000x reference)
//
#include <hip/hip_runtime.h>
#include <stdint.h>

typedef __attribute__((ext_vector_type(8))) short bf16x8;
typedef __attribute__((ext_vector_type(4))) float f32x4;

#define N_NODES 8192
#define E_EDGES 163840
#define NGRAPH  32
#define CHUNK   40960
#define NCHUNK  4

#define INV_SQRT30 0.18257419f
#define SH0C       0.22360680f   /* 1/sqrt(20) */
#define SQRT3C     1.73205081f
#define INV_SQRT3  0.57735027f
#define INV_SQRT10 0.31622777f
#define SQ2C       0.70710678f

// ---------------- workspace layout (bytes) ----------------
enum : unsigned {
  OFF_W1P1 = 0u,       OFF_W2P1 = 65536u,   OFF_W3P1 = 589824u,  OFF_W4P1 = 655360u,
  OFF_W1P2 = 851968u,  OFF_W2P2 = 917504u,  OFF_W3P2 = 1441792u, OFF_W4P2 = 1507328u,
  OFF_B1P1 = 1515520u, OFF_B2P1 = 1517568u, OFF_B3P1 = 1519616u, OFF_B4P1 = 1519872u,
  OFF_B1P2 = 1526016u, OFF_B2P2 = 1528064u, OFF_B3P2 = 1530112u, OFF_B4P2 = 1530368u,
  OFF_HN   = 1530624u, // [8192][32] f32
  OFF_H2   = 2579200u, // [8192][64] f32
  OFF_AGG  = 4676352u, // [8192][70] f32
  OFF_AGG2 = 6970112u, // [8192] f32
  OFF_GSUM = 7002880u, // [32] f32
  OFF_ZEND = 7003008u,
  OFF_SHL  = 7003136u, // [E][3] f32
  OFF_BAS  = 8969216u, // [E][64] bf16 (linear)
  OFF_ACT1 = 29940736u, // [CHUNK][512] bf16
  OFF_ACT2 = 71883776u, // [CHUNK][512] bf16
  OFF_X3   = 113826816u // [CHUNK][64] bf16
};

__device__ __forceinline__ uint16_t f2bf(float f){
  union { float f; uint32_t u; } v; v.f = f;
  uint32_t r = v.u + 0x7fffu + ((v.u >> 16) & 1u);
  return (uint16_t)(r >> 16);
}
__device__ __forceinline__ float swishf(float x){ return x / (1.f + __expf(-x)); }

// ---------------- weight pre-pack (f32 src -> bf16 MFMA B-fragment order) ----------------
__device__ __forceinline__ void pack_mat(const float* __restrict__ src, int K, int N, int NP,
                                         uint16_t* __restrict__ dst, int t)
{
  int lane = t & 63;
  int tile = t >> 6;
  int NT = NP >> 4;
  int nn = tile % NT, kk = tile / NT;
  int k0 = kk*32 + ((lane >> 4) << 3);
  int n  = nn*16 + (lane & 15);
  union { short s[8]; bf16x8 v; } tmp;
#pragma unroll
  for (int b = 0; b < 8; ++b) {
    int k = k0 + b;
    tmp.s[b] = (k < K && n < N) ? (short)f2bf(src[(size_t)k*N + n]) : (short)0;
  }
  *reinterpret_cast<bf16x8*>(dst + (size_t)t*8) = tmp.v;
}

__global__ void prep_kernel(const float* w1a, const float* w2a, const float* w3a, const float* w4a,
                            const float* w1b, const float* w2b, const float* w3b, const float* w4b,
                            const float* b1a, const float* b2a, const float* b3a, const float* b4a,
                            const float* b1b, const float* b2b, const float* b3b, const float* b4b,
                            const float* emb, const int* z, char* ws)
{
  int t = blockIdx.x * 256 + threadIdx.x;
  if      (t < 4096)   pack_mat(w1a, 40, 500, 512,  (uint16_t*)(ws + OFF_W1P1), t);
  else if (t < 36864)  pack_mat(w2a, 500,500, 512,  (uint16_t*)(ws + OFF_W2P1), t - 4096);
  else if (t < 40960)  pack_mat(w3a, 500, 50, 64,   (uint16_t*)(ws + OFF_W3P1), t - 36864);
  else if (t < 53248)  pack_mat(w4a, 50,1500, 1536, (uint16_t*)(ws + OFF_W4P1), t - 40960);
  else if (t < 57344)  pack_mat(w1b, 40, 500, 512,  (uint16_t*)(ws + OFF_W1P2), t - 53248);
  else if (t < 90112)  pack_mat(w2b, 500,500, 512,  (uint16_t*)(ws + OFF_W2P2), t - 57344);
  else if (t < 94208)  pack_mat(w3b, 500, 50, 64,   (uint16_t*)(ws + OFF_W3P2), t - 90112);
  else if (t < 94720)  pack_mat(w4b, 50,  40, 64,   (uint16_t*)(ws + OFF_W4P2), t - 94208);
  else if (t < 98496) {
    int loc = t - 94720;
    const float* src; float* dst; int realN;
    if      (loc < 512)  { src=b1a; dst=(float*)(ws+OFF_B1P1); realN=500; }
    else if (loc < 1024) { src=b2a; dst=(float*)(ws+OFF_B2P1); realN=500;  loc -= 512;  }
    else if (loc < 1088) { src=b3a; dst=(float*)(ws+OFF_B3P1); realN=50;   loc -= 1024; }
    else if (loc < 2624) { src=b4a; dst=(float*)(ws+OFF_B4P1); realN=1500; loc -= 1088; }
    else if (loc < 3136) { src=b1b; dst=(float*)(ws+OFF_B1P2); realN=500;  loc -= 2624; }
    else if (loc < 3648) { src=b2b; dst=(float*)(ws+OFF_B2P2); realN=500;  loc -= 3136; }
    else if (loc < 3712) { src=b3b; dst=(float*)(ws+OFF_B3P2); realN=50;   loc -= 3648; }
    else                 { src=b4b; dst=(float*)(ws+OFF_B4P2); realN=40;   loc -= 3712; }
    dst[loc] = (loc < realN) ? src[loc] : 0.f;
  }
  else if (t < 360640) {
    int i = t - 98496;
    int n = i >> 5, u = i & 31;
    float v = 0.f;
    if (u < 30) v = emb[(size_t)z[n]*30 + u] * INV_SQRT30;
    ((float*)(ws + OFF_HN))[i] = v;
  }
}

// ---------------- edge meta ----------------
__global__ void edge_meta(const float* __restrict__ pos, const int* __restrict__ eidx,
                          uint16_t* __restrict__ basis, float* __restrict__ shl)
{
  int e = blockIdx.x * 256 + threadIdx.x;
  if (e >= E_EDGES) return;
  int rn = eidx[e], cn = eidx[E_EDGES + e];
  float ax = pos[rn*3+0] - pos[cn*3+0];
  float ay = pos[rn*3+1] - pos[cn*3+1];
  float az = pos[rn*3+2] - pos[cn*3+2];
  float rr = sqrtf(ax*ax + ay*ay + az*az + 1e-12f);
  float s = SQRT3C * SH0C / rr;
  shl[e*3+0] = ax*s; shl[e*3+1] = ay*s; shl[e*3+2] = az*s;
#pragma unroll
  for (int j = 0; j < 8; ++j) {
    union { short s[8]; bf16x8 v; } tmp;
#pragma unroll
    for (int b = 0; b < 8; ++b) {
      int c = j*8 + b;
      float vv = 0.f;
      if (c < 40) { float t = rr*3.9f - (float)c; vv = __expf(-t*t); }
      tmp.s[b] = (short)f2bf(vv);
    }
    *reinterpret_cast<bf16x8*>(basis + (size_t)e*64 + j*8) = tmp.v;
  }
}

// ---------------- big GEMM + swish: 256x256 tile, 8 waves, N=512 ----------------
template<int KP>
__global__ __launch_bounds__(512, 2)
void gemm_big(const uint16_t* __restrict__ A, const uint16_t* __restrict__ Bp,
              const float* __restrict__ bias, uint16_t* __restrict__ Out)
{
  constexpr int NSTG = KP / 64;
  constexpr int DB   = (NSTG > 1) ? 2 : 1;
  constexpr int ASZ  = 32768;
  constexpr int BSZ  = 32768;

  __shared__ __align__(16) char lsA[DB * ASZ];
  __shared__ __align__(16) char lsB[DB * BSZ];

  const int tid = threadIdx.x, lane = tid & 63, wv = tid >> 6;
  // bijective XCD swizzle: grid = 320 = 8 * 40
  const int b = blockIdx.x;
  const int xcd = b & 7, slot = b >> 3;
  const int ntb = slot & 1;
  const int mt  = (slot >> 1) * 8 + xcd;
  const int m0  = mt * 256;
  const int wrow = (wv >> 2) * 128;       // wave rows: 128
  const int wcol = (wv & 3) * 4;          // wave ntiles (of 16 cols): 4 -> 64 cols

  f32x4 acc[8][4];
  f32x4 zv = {0.f, 0.f, 0.f, 0.f};
#pragma unroll
  for (int a = 0; a < 8; ++a)
#pragma unroll
    for (int c = 0; c < 4; ++c) acc[a][c] = zv;

  auto stageA = [&](int buf, int kg0) {
#pragma unroll
    for (int j = 0; j < 4; ++j) {
      int base = (wv*4 + j) * 1024;
      int d = base + lane*16;
      int row = d >> 7;
      int colb = (d & 127) ^ ((row & 7) << 4);
      const char* src = (const char*)A + (size_t)(m0 + row)*(KP*2) + kg0*2 + colb;
      __builtin_amdgcn_global_load_lds((const __attribute__((address_space(1))) void*)src,
          (__attribute__((address_space(3))) void*)(&lsA[buf*ASZ + base]), 16, 0, 0);
    }
  };
  auto stageB = [&](int buf, int stg) {
#pragma unroll
    for (int j = 0; j < 4; ++j) {
      int inst = wv*4 + j;                 // 0..31
      int kk = inst >> 4;                  // 0..1
      int nn = inst & 15;                  // 0..15
      const char* src = (const char*)Bp + ((size_t)((stg*2 + kk)*32 + ntb*16 + nn) * 64) * 16 + lane*16;
      __builtin_amdgcn_global_load_lds((const __attribute__((address_space(1))) void*)src,
          (__attribute__((address_space(3))) void*)(&lsB[buf*BSZ + inst*1024]), 16, 0, 0);
    }
  };
  auto compute = [&](int buf) {
#pragma unroll
    for (int kk = 0; kk < 2; ++kk) {
      bf16x8 af[8];
#pragma unroll
      for (int rb = 0; rb < 8; ++rb) {
        int row = wrow + rb*16 + (lane & 15);
        int byte = (row*128 + kk*64 + (lane >> 4)*16) ^ ((row & 7) << 4);
        af[rb] = *reinterpret_cast<const bf16x8*>(&lsA[buf*ASZ + byte]);
      }
      bf16x8 bfr[4];
#pragma unroll
      for (int nt = 0; nt < 4; ++nt)
        bfr[nt] = *reinterpret_cast<const bf16x8*>(&lsB[buf*BSZ + ((kk*16 + wcol + nt)*64 + lane)*16]);
#pragma unroll
      for (int nt = 0; nt < 4; ++nt)
#pragma unroll
        for (int rb = 0; rb < 8; ++rb)
          acc[rb][nt] = __builtin_amdgcn_mfma_f32_16x16x32_bf16(af[rb], bfr[nt], acc[rb][nt], 0, 0, 0);
    }
  };

  stageA(0, 0); stageB(0, 0);
  asm volatile("s_waitcnt vmcnt(0)" ::: "memory");
  __builtin_amdgcn_s_barrier();

  int cur = 0;
#pragma unroll 1
  for (int s = 0; s < NSTG; ++s) {
    if (DB == 2 && s + 1 < NSTG) { stageA(cur ^ 1, (s + 1) * 64); stageB(cur ^ 1, s + 1); }
    compute(cur);
    if (s + 1 < NSTG) {
      asm volatile("s_waitcnt vmcnt(0)" ::: "memory");
      __builtin_amdgcn_s_barrier();
      cur ^= 1;
    }
  }

  const int r = lane & 15, q = lane >> 4;
#pragma unroll
  for (int nt = 0; nt < 4; ++nt) {
    int col = ntb*256 + (wcol + nt)*16 + r;
    float bs = bias[col];
#pragma unroll
    for (int rb = 0; rb < 8; ++rb)
#pragma unroll
      for (int i = 0; i < 4; ++i) {
        int row = m0 + wrow + rb*16 + q*4 + i;
        Out[(size_t)row*512 + col] = f2bf(swishf(acc[rb][nt][i] + bs));
      }
  }
}

// ---------------- small GEMM + swish (K=512 -> N=64), 128-row tiles ----------------
__global__ __launch_bounds__(256)
void gemm_small(const uint16_t* __restrict__ A, const uint16_t* __restrict__ Bp,
                const float* __restrict__ bias, uint16_t* __restrict__ Out)
{
  constexpr int KP = 512, NSTG = 8;
  constexpr int ASZ = 16384, BSZ = 8192;

  __shared__ __align__(16) char lsA[2 * ASZ];
  __shared__ __align__(16) char lsB[2 * BSZ];

  const int tid = threadIdx.x, lane = tid & 63, wv = tid >> 6;
  const int m0 = blockIdx.x * 128;
  const int wrow = wv * 32;

  f32x4 acc[2][4];
  f32x4 zv = {0.f, 0.f, 0.f, 0.f};
#pragma unroll
  for (int a = 0; a < 2; ++a)
#pragma unroll
    for (int c = 0; c < 4; ++c) acc[a][c] = zv;

  auto stageA = [&](int buf, int kg0) {
#pragma unroll
    for (int j = 0; j < 4; ++j) {
      int base = (wv*4 + j) * 1024;
      int d = base + lane*16;
      int row = d >> 7;
      int colb = (d & 127) ^ ((row & 7) << 4);
      const char* src = (const char*)A + (size_t)(m0 + row)*(KP*2) + kg0*2 + colb;
      __builtin_amdgcn_global_load_lds((const __attribute__((address_space(1))) void*)src,
          (__attribute__((address_space(3))) void*)(&lsA[buf*ASZ + base]), 16, 0, 0);
    }
  };
  auto stageB = [&](int buf, int stg) {
#pragma unroll
    for (int j = 0; j < 2; ++j) {
      int inst = wv*2 + j;                 // 0..7
      int kk = inst >> 2;
      int nn = inst & 3;
      const char* src = (const char*)Bp + ((size_t)((stg*2 + kk)*4 + nn) * 64) * 16 + lane*16;
      __builtin_amdgcn_global_load_lds((const __attribute__((address_space(1))) void*)src,
          (__attribute__((address_space(3))) void*)(&lsB[buf*BSZ + inst*1024]), 16, 0, 0);
    }
  };
  auto compute = [&](int buf) {
#pragma unroll
    for (int kk = 0; kk < 2; ++kk) {
      bf16x8 af[2];
#pragma unroll
      for (int rb = 0; rb < 2; ++rb) {
        int row = wrow + rb*16 + (lane & 15);
        int byte = (row*128 + kk*64 + (lane >> 4)*16) ^ ((row & 7) << 4);
        af[rb] = *reinterpret_cast<const bf16x8*>(&lsA[buf*ASZ + byte]);
      }
      bf16x8 bfr[4];
#pragma unroll
      for (int nt = 0; nt < 4; ++nt)
        bfr[nt] = *reinterpret_cast<const bf16x8*>(&lsB[buf*BSZ + ((kk*4 + nt)*64 + lane)*16]);
#pragma unroll
      for (int nt = 0; nt < 4; ++nt)
#pragma unroll
        for (int rb = 0; rb < 2; ++rb)
          acc[rb][nt] = __builtin_amdgcn_mfma_f32_16x16x32_bf16(af[rb], bfr[nt], acc[rb][nt], 0, 0, 0);
    }
  };

  stageA(0, 0); stageB(0, 0);
  asm volatile("s_waitcnt vmcnt(0)" ::: "memory");
  __builtin_amdgcn_s_barrier();

  int cur = 0;
#pragma unroll 1
  for (int s = 0; s < NSTG; ++s) {
    if (s + 1 < NSTG) { stageA(cur ^ 1, (s + 1) * 64); stageB(cur ^ 1, s + 1); }
    compute(cur);
    if (s + 1 < NSTG) {
      asm volatile("s_waitcnt vmcnt(0)" ::: "memory");
      __builtin_amdgcn_s_barrier();
      cur ^= 1;
    }
  }

  const int r = lane & 15, q = lane >> 4;
#pragma unroll
  for (int nt = 0; nt < 4; ++nt) {
    int col = nt*16 + r;
    float bs = bias[col];
#pragma unroll
    for (int rb = 0; rb < 2; ++rb)
#pragma unroll
      for (int i = 0; i < 4; ++i) {
        int row = m0 + wrow + rb*16 + q*4 + i;
        Out[(size_t)row*64 + col] = f2bf(swishf(acc[rb][nt][i] + bs));
      }
  }
}

// ---------------- TP layer 1 (atomic-free consumption, f32 w-tile) ----------------
__global__ __launch_bounds__(512)
void tp1_kernel(const uint16_t* __restrict__ x3, const char* __restrict__ ws,
                const int* __restrict__ eidx, float* __restrict__ agg, int ec0)
{
  constexpr int P1 = 1537;            // f32 pitch (odd -> rows bank-shifted)
  __shared__ float wbuf[16 * P1];
  __shared__ float xjb[64*30];
  __shared__ float mbuf[64*50];
  __shared__ float shls[64*3];
  __shared__ int   rowl[64];
  __shared__ int   coll[64];

  const float* hN  = (const float*)(ws + OFF_HN);
  const float* shl = (const float*)(ws + OFF_SHL);
  const float* b4p = (const float*)(ws + OFF_B4P1);
  const bf16x8* __restrict__ bv4 = (const bf16x8*)(ws + OFF_W4P1);

  const int tid = threadIdx.x, lane = tid & 63, wv = tid >> 6;
  const int e0l = blockIdx.x * 64;
  const int eg0 = ec0 + e0l;
  const int r_ = lane & 15, q_ = lane >> 4;

  if (tid < 64) { rowl[tid] = eidx[eg0 + tid]; coll[tid] = eidx[E_EDGES + eg0 + tid]; }
  for (int i = tid; i < 192; i += 512) shls[i] = shl[(size_t)eg0*3 + i];
  __syncthreads();
  for (int i = tid; i < 64*30; i += 512) {
    int e = i/30, u = i - e*30;
    xjb[i] = hN[(size_t)rowl[e]*32 + u];
  }

  const int eo = tid >> 5;    // edge within 16-edge subtile
  const int pr = tid & 31;    // output pair index (active < 25)
  f32x4 zv = {0.f, 0.f, 0.f, 0.f};

#pragma unroll 1
  for (int st = 0; st < 4; ++st) {
    bf16x8 a0, a1;
    {
      int row = e0l + st*16 + r_;
      const char* base = (const char*)x3 + (size_t)row*128 + q_*16;
      a0 = *reinterpret_cast<const bf16x8*>(base);
      a1 = *reinterpret_cast<const bf16x8*>(base + 64);
    }
    f32x4 acc[12];
#pragma unroll
    for (int j = 0; j < 12; ++j) acc[j] = zv;
#pragma unroll
    for (int j = 0; j < 12; ++j) {
      int g = wv*12 + j;
      acc[j] = __builtin_amdgcn_mfma_f32_16x16x32_bf16(a0, bv4[(size_t)g*64 + lane], acc[j], 0, 0, 0);
      acc[j] = __builtin_amdgcn_mfma_f32_16x16x32_bf16(a1, bv4[(size_t)(96 + g)*64 + lane], acc[j], 0, 0, 0);
    }
    __syncthreads();
#pragma unroll
    for (int j = 0; j < 12; ++j) {
      int cg = (wv*12 + j)*16 + r_;
      float bs = b4p[cg];
#pragma unroll
      for (int i = 0; i < 4; ++i) {
        int e = q_*4 + i;
        wbuf[e*P1 + cg] = acc[j][i] + bs;
      }
    }
    __syncthreads();

    if (pr < 25) {
      int eL = st*16 + eo;
      float s0 = 0.f, s1 = 0.f;
      if (pr < 20) {
        int c = 2*pr;
        const float* wrow_ = &wbuf[eo*P1 + c];
        const float* xr = &xjb[eL*30];
#pragma unroll
        for (int u = 0; u < 30; ++u) {
          float xv = xr[u];
          s0 += xv * wrow_[u*40];
          s1 += xv * wrow_[u*40 + 1];
        }
        mbuf[eL*50 + c]     = s0;
        mbuf[eL*50 + c + 1] = s1;
      } else {
        int vv = 2*(pr - 20);
        const float* wrow_ = &wbuf[eo*P1 + 1200 + vv];
        const float* xr = &xjb[eL*30];
#pragma unroll
        for (int u = 0; u < 30; ++u) {
          float xv = xr[u];
          s0 += xv * wrow_[u*10];
          s1 += xv * wrow_[u*10 + 1];
        }
        mbuf[eL*50 + 40 + vv] = s0;
        mbuf[eL*50 + 41 + vv] = s1;
      }
    }
  }
  __syncthreads();

#pragma unroll 1
  for (int i = tid; i < 64*70; i += 512) {
    int e = i/70, c = i - e*70;
    float v;
    if (c < 40) v = mbuf[e*50 + c] * SH0C;
    else { int vv = (c - 40)/3, k = (c - 40) - vv*3; v = mbuf[e*50 + 40 + vv] * shls[e*3 + k]; }
    atomicAdd(&agg[(size_t)coll[e]*70 + c], v);
  }
}

// ---------------- TP layer 2 (atomic-free consumption, f32 w-tile) ----------------
__global__ __launch_bounds__(512, 2)
void tp2_kernel(const uint16_t* __restrict__ x3, const char* __restrict__ ws,
                const int* __restrict__ eidx, float* __restrict__ agg2, int ec0)
{
  constexpr int P2 = 67;
  __shared__ float wbuf2[64 * P2];
  __shared__ float xjs[64*30];
  __shared__ float xjv[64*30];
  __shared__ float Db[64*10];
  __shared__ float shls[64*3];
  __shared__ int   rowl[64];
  __shared__ int   coll[64];

  const float* h2  = (const float*)(ws + OFF_H2);
  const float* shl = (const float*)(ws + OFF_SHL);
  const float* b4p = (const float*)(ws + OFF_B4P2);
  const bf16x8* __restrict__ bv4 = (const bf16x8*)(ws + OFF_W4P2);

  const int tid = threadIdx.x, lane = tid & 63, wv = tid >> 6;
  const int e0l = blockIdx.x * 64;
  const int eg0 = ec0 + e0l;
  const int r_ = lane & 15, q_ = lane >> 4;

  if (tid < 64) { rowl[tid] = eidx[eg0 + tid]; coll[tid] = eidx[E_EDGES + eg0 + tid]; }
  for (int i = tid; i < 192; i += 512) shls[i] = shl[(size_t)eg0*3 + i];
  __syncthreads();
  for (int i = tid; i < 64*60; i += 512) {
    int e = i/60, u = i - e*60;
    float v = h2[(size_t)rowl[e]*64 + u];
    if (u < 30) xjs[e*30 + u] = v; else xjv[e*30 + (u - 30)] = v;
  }
  __syncthreads();
  for (int i = tid; i < 640; i += 512) {
    int e = i/10, v = i - e*10;
    float d = 0.f;
#pragma unroll
    for (int m = 0; m < 3; ++m) d += xjv[e*30 + v*3 + m] * shls[e*3 + m];
    Db[i] = d * INV_SQRT3;
  }

  const int rbase = (wv >> 2)*2, nt4 = wv & 3;
  bf16x8 a4[2][2];
#pragma unroll
  for (int kk = 0; kk < 2; ++kk)
#pragma unroll
    for (int rbi = 0; rbi < 2; ++rbi) {
      int row = e0l + (rbase + rbi)*16 + r_;
      a4[kk][rbi] = *reinterpret_cast<const bf16x8*>((const char*)x3 + (size_t)row*128 + kk*64 + q_*16);
    }
  f32x4 acc[2];
  f32x4 zv = {0.f, 0.f, 0.f, 0.f};
  acc[0] = zv; acc[1] = zv;
#pragma unroll
  for (int kk = 0; kk < 2; ++kk) {
    bf16x8 b4 = bv4[(size_t)(kk*4 + nt4)*64 + lane];
#pragma unroll
    for (int rbi = 0; rbi < 2; ++rbi)
      acc[rbi] = __builtin_amdgcn_mfma_f32_16x16x32_bf16(a4[kk][rbi], b4, acc[rbi], 0, 0, 0);
  }
  __syncthreads();
  {
    int cg = nt4*16 + r_;
    float bs = b4p[cg];
#pragma unroll
    for (int rbi = 0; rbi < 2; ++rbi)
#pragma unroll
      for (int i2 = 0; i2 < 4; ++i2) {
        int e = (rbase + rbi)*16 + q_*4 + i2;
        wbuf2[e*P2 + cg] = acc[rbi][i2] + bs;
      }
  }
  __syncthreads();

  if (tid < 64) {
    int e = tid;
    float m = 0.f, m2 = 0.f;
#pragma unroll
    for (int c = 0; c < 30; ++c) m += xjs[e*30 + c] * wbuf2[e*P2 + c];
#pragma unroll
    for (int vv = 0; vv < 10; ++vv) m2 += Db[e*10 + vv] * wbuf2[e*P2 + 30 + vv];
    atomicAdd(&agg2[coll[e]], m * (SH0C * INV_SQRT30) + m2 * INV_SQRT10);
  }
}

// ---------------- node kernels ----------------
__global__ void node_mid(char* ws, const float* __restrict__ si1w)
{
  int nid = blockIdx.x * blockDim.x + threadIdx.x;
  if (nid >= N_NODES) return;
  const float* hN  = (const float*)(ws + OFF_HN)  + (size_t)nid*32;
  const float* agg = (const float*)(ws + OFF_AGG) + (size_t)nid*70;
  float* h2        = (float*)(ws + OFF_H2)        + (size_t)nid*64;

  float hn[30];
#pragma unroll
  for (int u = 0; u < 30; ++u) hn[u] = hN[u];

  float h1[70];
#pragma unroll 1
  for (int v = 0; v < 40; ++v) {
    float s = 0.f;
#pragma unroll
    for (int u = 0; u < 30; ++u) s += hn[u] * si1w[u*40 + v];
    h1[v] = SQ2C * (s + agg[v]);
  }
#pragma unroll
  for (int c = 40; c < 70; ++c) h1[c] = agg[c];

#pragma unroll
  for (int u = 0; u < 30; ++u) h2[u] = swishf(h1[u]);
#pragma unroll
  for (int v = 0; v < 10; ++v) {
    float g = 1.f / (1.f + __expf(-h1[30 + v]));
#pragma unroll
    for (int k = 0; k < 3; ++k) h2[30 + v*3 + k] = h1[40 + v*3 + k] * g;
  }
}

__global__ void node_final(char* ws, const float* __restrict__ si2w, const int* __restrict__ batch)
{
  __shared__ float ls[NGRAPH];
  if (threadIdx.x < NGRAPH) ls[threadIdx.x] = 0.f;
  __syncthreads();
  int nid = blockIdx.x * blockDim.x + threadIdx.x;
  if (nid < N_NODES) {
    const float* h2   = (const float*)(ws + OFF_H2) + (size_t)nid*64;
    const float* agg2 = (const float*)(ws + OFF_AGG2);
    float s2 = 0.f;
#pragma unroll
    for (int u = 0; u < 30; ++u) s2 += h2[u] * si2w[u];
    float val = SQ2C * (s2 * INV_SQRT30 + agg2[nid]);
    atomicAdd(&ls[batch[nid]], val);
  }
  __syncthreads();
  if (threadIdx.x < NGRAPH)
    atomicAdd(((float*)(ws + OFF_GSUM)) + threadIdx.x, ls[threadIdx.x]);
}

__global__ void write_out(const char* ws, float* out)
{
  int g = threadIdx.x;
  if (g < NGRAPH) out[g] = ((const float*)(ws + OFF_GSUM))[g];
}

// ---------------- launch ----------------
extern "C" void kernel_launch(void* const* d_in, const int* in_sizes, int n_in,
                              void* d_out, int out_size, void* d_ws, size_t ws_size,
                              hipStream_t stream)
{
  const float* pos  = (const float*)d_in[0];
  const float* emb  = (const float*)d_in[1];
  const float* si1w = (const float*)d_in[2];
  const float* si2w = (const float*)d_in[3];
  const float* w1a = (const float*)d_in[4];  const float* b1a = (const float*)d_in[5];
  const float* w2a = (const float*)d_in[6];  const float* b2a = (const float*)d_in[7];
  const float* w3a = (const float*)d_in[8];  const float* b3a = (const float*)d_in[9];
  const float* w4a = (const float*)d_in[10]; const float* b4a = (const float*)d_in[11];
  const float* w1b = (const float*)d_in[12]; const float* b1b = (const float*)d_in[13];
  const float* w2b = (const float*)d_in[14]; const float* b2b = (const float*)d_in[15];
  const float* w3b = (const float*)d_in[16]; const float* b3b = (const float*)d_in[17];
  const float* w4b = (const float*)d_in[18]; const float* b4b = (const float*)d_in[19];
  const int* z     = (const int*)d_in[20];
  const int* eidx  = (const int*)d_in[21];
  const int* batch = (const int*)d_in[22];
  char* ws = (char*)d_ws;

  uint16_t* basis = (uint16_t*)(ws + OFF_BAS);
  float*    shl   = (float*)(ws + OFF_SHL);
  uint16_t* act1  = (uint16_t*)(ws + OFF_ACT1);
  uint16_t* act2  = (uint16_t*)(ws + OFF_ACT2);
  uint16_t* x3    = (uint16_t*)(ws + OFF_X3);

  hipMemsetAsync(ws + OFF_AGG, 0, OFF_ZEND - OFF_AGG, stream);

  prep_kernel<<<1409, 256, 0, stream>>>(w1a, w2a, w3a, w4a, w1b, w2b, w3b, w4b,
                                        b1a, b2a, b3a, b4a, b1b, b2b, b3b, b4b,
                                        emb, z, ws);
  edge_meta<<<E_EDGES/256, 256, 0, stream>>>(pos, eidx, basis, shl);

  // ---- layer 1 ----
  for (int c = 0; c < NCHUNK; ++c) {
    const uint16_t* basc = basis + (size_t)c*CHUNK*64;
    gemm_big<64><<<(CHUNK/256)*2, 512, 0, stream>>>(basc, (const uint16_t*)(ws + OFF_W1P1),
                                                    (const float*)(ws + OFF_B1P1), act1);
    gemm_big<512><<<(CHUNK/256)*2, 512, 0, stream>>>(act1, (const uint16_t*)(ws + OFF_W2P1),
                                                     (const float*)(ws + OFF_B2P1), act2);
    gemm_small<<<CHUNK/128, 256, 0, stream>>>(act2, (const uint16_t*)(ws + OFF_W3P1),
                                              (const float*)(ws + OFF_B3P1), x3);
    tp1_kernel<<<CHUNK/64, 512, 0, stream>>>(x3, ws, eidx, (float*)(ws + OFF_AGG), c*CHUNK);
  }

  node_mid<<<N_NODES/256, 256, 0, stream>>>(ws, si1w);

  // ---- layer 2 ----
  for (int c = 0; c < NCHUNK; ++c) {
    const uint16_t* basc = basis + (size_t)c*CHUNK*64;
    gemm_big<64><<<(CHUNK/256)*2, 512, 0, stream>>>(basc, (const uint16_t*)(ws + OFF_W1P2),
                                                    (const float*)(ws + OFF_B1P2), act1);
    gemm_big<512><<<(CHUNK/256)*2, 512, 0, stream>>>(act1, (const uint16_t*)(ws + OFF_W2P2),
                                                     (const float*)(ws + OFF_B2P2), act2);
    gemm_small<<<CHUNK/128, 256, 0, stream>>>(act2, (const uint16_t*)(ws + OFF_W3P2),
                                              (const float*)(ws + OFF_B3P2), x3);
    tp2_kernel<<<CHUNK/64, 512, 0, stream>>>(x3, ws, eidx, (float*)(ws + OFF_AGG2), c*CHUNK);
  }

  node_final<<<N_NODES/256, 256, 0, stream>>>(ws, si2w, batch);
  write_out<<<1, 64, 0, stream>>>(ws, (float*)d_out);
}

// Round 15
// 806.721 us; speedup vs baseline: 1.3085x; 1.3085x over previous
//
#include <hip/hip_runtime.h>
#include <stdint.h>

typedef __attribute__((ext_vector_type(8))) short bf16x8;
typedef __attribute__((ext_vector_type(4))) float f32x4;

#define N_NODES 8192
#define E_EDGES 163840
#define NGRAPH  32
#define CHUNK   32768
#define NCHUNK  5

#define INV_SQRT30 0.18257419f
#define SH0C       0.22360680f   /* 1/sqrt(20) */
#define SQRT3C     1.73205081f
#define INV_SQRT3  0.57735027f
#define INV_SQRT10 0.31622777f
#define SQ2C       0.70710678f

// ---------------- workspace layout (bytes) ----------------
enum : unsigned {
  OFF_W1P1 = 0u,       OFF_W2P1 = 65536u,   OFF_W3P1 = 589824u,  OFF_W4P1 = 655360u,
  OFF_W1P2 = 851968u,  OFF_W2P2 = 917504u,  OFF_W3P2 = 1441792u, OFF_W4P2 = 1507328u,
  OFF_B1P1 = 1515520u, OFF_B2P1 = 1517568u, OFF_B3P1 = 1519616u, OFF_B4P1 = 1519872u,
  OFF_B1P2 = 1526016u, OFF_B2P2 = 1528064u, OFF_B3P2 = 1530112u, OFF_B4P2 = 1530368u,
  OFF_HN   = 1530624u, // [8192][32] f32
  OFF_H2   = 2579200u, // [8192][64] f32
  OFF_AGG  = 4676352u, // [8192][70] f32
  OFF_AGG2 = 6970112u, // [8192] f32
  OFF_GSUM = 7002880u, // [32] f32
  OFF_ZEND = 7003008u,
  OFF_SHL  = 7003136u,  // [E][3] f32
  OFF_BAS  = 8969216u,  // [E][64] bf16 (linear)
  OFF_ACT1 = 29940736u, // [CHUNK][512] bf16
  OFF_ACT2 = 63495168u, // [CHUNK][512] bf16
  OFF_X3   = 97049600u, // [CHUNK][64] bf16
  OFF_W4N1 = 101243904u // 30 steps x 8 tiles x 1KB = 245760 B
};

__device__ __forceinline__ uint16_t f2bf(float f){
  union { float f; uint32_t u; } v; v.f = f;
  uint32_t r = v.u + 0x7fffu + ((v.u >> 16) & 1u);
  return (uint16_t)(r >> 16);
}
__device__ __forceinline__ float swishf(float x){ return x / (1.f + __expf(-x)); }

// ---------------- weight pre-pack (f32 src -> bf16 MFMA B-fragment order) ----------------
__device__ __forceinline__ void pack_mat(const float* __restrict__ src, int K, int N, int NP,
                                         uint16_t* __restrict__ dst, int t)
{
  int lane = t & 63;
  int tile = t >> 6;
  int NT = NP >> 4;
  int nn = tile % NT, kk = tile / NT;
  int k0 = kk*32 + ((lane >> 4) << 3);
  int n  = nn*16 + (lane & 15);
  union { short s[8]; bf16x8 v; } tmp;
#pragma unroll
  for (int b = 0; b < 8; ++b) {
    int k = k0 + b;
    tmp.s[b] = (k < K && n < N) ? (short)f2bf(src[(size_t)k*N + n]) : (short)0;
  }
  *reinterpret_cast<bf16x8*>(dst + (size_t)t*8) = tmp.v;
}

// W4' pack for tp1-as-GEMM: step u (0..29), tile j=kk*4+nn; rows k (x3 cols, 63=bias), cols n (0..49 real)
__device__ __forceinline__ void pack_w4n(const float* __restrict__ w4, const float* __restrict__ b4,
                                         uint16_t* __restrict__ dst, int t)
{
  int lane = t & 63;
  int tile = t >> 6;           // 0..239
  int u = tile >> 3, j = tile & 7;
  int kk = j >> 2, nn = j & 3;
  int k0 = kk*32 + ((lane >> 4) << 3);
  int n  = nn*16 + (lane & 15);
  union { short s[8]; bf16x8 v; } tmp;
#pragma unroll
  for (int b = 0; b < 8; ++b) {
    int k = k0 + b;
    float val = 0.f;
    if (n < 50) {
      int cg = (n < 40) ? (u*40 + n) : (1200 + u*10 + (n - 40));
      if (k < 50) val = w4[(size_t)k*1500 + cg];
      else if (k == 63) val = b4[cg];
    }
    tmp.s[b] = (short)f2bf(val);
  }
  *reinterpret_cast<bf16x8*>(dst + (size_t)t*8) = tmp.v;
}

__global__ void prep_kernel(const float* w1a, const float* w2a, const float* w3a, const float* w4a,
                            const float* w1b, const float* w2b, const float* w3b, const float* w4b,
                            const float* b1a, const float* b2a, const float* b3a, const float* b4a,
                            const float* b1b, const float* b2b, const float* b3b, const float* b4b,
                            const float* emb, const int* z, char* ws)
{
  int t = blockIdx.x * 256 + threadIdx.x;
  if      (t < 4096)   pack_mat(w1a, 40, 500, 512,  (uint16_t*)(ws + OFF_W1P1), t);
  else if (t < 36864)  pack_mat(w2a, 500,500, 512,  (uint16_t*)(ws + OFF_W2P1), t - 4096);
  else if (t < 40960)  pack_mat(w3a, 500, 50, 64,   (uint16_t*)(ws + OFF_W3P1), t - 36864);
  else if (t < 45056)  { /* spare */ }
  else if (t < 49152)  pack_mat(w1b, 40, 500, 512,  (uint16_t*)(ws + OFF_W1P2), t - 45056);
  else if (t < 81920)  pack_mat(w2b, 500,500, 512,  (uint16_t*)(ws + OFF_W2P2), t - 49152);
  else if (t < 86016)  pack_mat(w3b, 500, 50, 64,   (uint16_t*)(ws + OFF_W3P2), t - 81920);
  else if (t < 86528)  pack_mat(w4b, 50,  40, 64,   (uint16_t*)(ws + OFF_W4P2), t - 86016);
  else if (t < 90304) {
    int loc = t - 86528;
    const float* src; float* dst; int realN;
    if      (loc < 512)  { src=b1a; dst=(float*)(ws+OFF_B1P1); realN=500; }
    else if (loc < 1024) { src=b2a; dst=(float*)(ws+OFF_B2P1); realN=500;  loc -= 512;  }
    else if (loc < 1088) { src=b3a; dst=(float*)(ws+OFF_B3P1); realN=50;   loc -= 1024; }
    else if (loc < 2624) { src=b4a; dst=(float*)(ws+OFF_B4P1); realN=1500; loc -= 1088; }
    else if (loc < 3136) { src=b1b; dst=(float*)(ws+OFF_B1P2); realN=500;  loc -= 2624; }
    else if (loc < 3648) { src=b2b; dst=(float*)(ws+OFF_B2P2); realN=500;  loc -= 3136; }
    else if (loc < 3712) { src=b3b; dst=(float*)(ws+OFF_B3P2); realN=50;   loc -= 3648; }
    else                 { src=b4b; dst=(float*)(ws+OFF_B4P2); realN=40;   loc -= 3712; }
    dst[loc] = (loc < realN) ? src[loc] : 0.f;
  }
  else if (t < 352448) {
    int i = t - 90304;
    int n = i >> 5, u = i & 31;
    float v = 0.f;
    if (u < 30) v = emb[(size_t)z[n]*30 + u] * INV_SQRT30;
    ((float*)(ws + OFF_HN))[i] = v;
  }
  else if (t < 367808) {
    pack_w4n(w4a, b4a, (uint16_t*)(ws + OFF_W4N1), t - 352448);
  }
}

// ---------------- edge meta ----------------
__global__ void edge_meta(const float* __restrict__ pos, const int* __restrict__ eidx,
                          uint16_t* __restrict__ basis, float* __restrict__ shl)
{
  int e = blockIdx.x * 256 + threadIdx.x;
  if (e >= E_EDGES) return;
  int rn = eidx[e], cn = eidx[E_EDGES + e];
  float ax = pos[rn*3+0] - pos[cn*3+0];
  float ay = pos[rn*3+1] - pos[cn*3+1];
  float az = pos[rn*3+2] - pos[cn*3+2];
  float rr = sqrtf(ax*ax + ay*ay + az*az + 1e-12f);
  float s = SQRT3C * SH0C / rr;
  shl[e*3+0] = ax*s; shl[e*3+1] = ay*s; shl[e*3+2] = az*s;
#pragma unroll
  for (int j = 0; j < 8; ++j) {
    union { short s[8]; bf16x8 v; } tmp;
#pragma unroll
    for (int b = 0; b < 8; ++b) {
      int c = j*8 + b;
      float vv = 0.f;
      if (c < 40) { float t = rr*3.9f - (float)c; vv = __expf(-t*t); }
      tmp.s[b] = (short)f2bf(vv);
    }
    *reinterpret_cast<bf16x8*>(basis + (size_t)e*64 + j*8) = tmp.v;
  }
}

// ---------------- batched GEMM + swish (round-13 structure: DB=2 + XCD swizzle) ----------------
template<int KP, int NP, bool SET63>
__global__ __launch_bounds__(256)
void gemm_swish(const uint16_t* __restrict__ A, const uint16_t* __restrict__ Bp,
                const float* __restrict__ bias, uint16_t* __restrict__ Out)
{
  constexpr int BN   = (NP == 512) ? 128 : 64;
  constexpr int NBN  = BN / 16;
  constexpr int NT   = NP / 16;
  constexpr int NSTG = KP / 64;
  constexpr int DB   = (NSTG > 1) ? 2 : 1;
  constexpr int RB   = (NP == 512) ? 4 : 2;
  constexpr int ASZ  = 16384;
  constexpr int BSZ  = NBN * 2048;

  __shared__ __align__(16) char lsA[DB * ASZ];
  __shared__ __align__(16) char lsB[DB * BSZ];

  const int tid = threadIdx.x, lane = tid & 63, wv = tid >> 6;
  int mt, ntb;
  if (NP == 512) {
    int b = blockIdx.x;
    int xcd = b & 7, slot = b >> 3;
    ntb = slot & 3;
    mt  = (slot >> 2) * 8 + xcd;      // grid = mts*4, mts % 8 == 0
  } else { ntb = 0; mt = blockIdx.x; }
  const int m0  = mt * 128;
  const int wrow = (NP == 512) ? (wv >> 1) * 64 : wv * 32;
  const int wntl = (NP == 512) ? (wv & 1) * 4 : 0;

  f32x4 acc[RB][4];
  f32x4 zv = {0.f, 0.f, 0.f, 0.f};
#pragma unroll
  for (int a = 0; a < RB; ++a)
#pragma unroll
    for (int b = 0; b < 4; ++b) acc[a][b] = zv;

  auto stageA = [&](int buf, int kg0) {
#pragma unroll
    for (int j = 0; j < 4; ++j) {
      int base = (wv*4 + j) * 1024;
      int d = base + lane*16;
      int row = d >> 7;
      int colb = (d & 127) ^ ((row & 7) << 4);
      const char* src = (const char*)A + (size_t)(m0 + row)*(KP*2) + kg0*2 + colb;
      __builtin_amdgcn_global_load_lds((const __attribute__((address_space(1))) void*)src,
          (__attribute__((address_space(3))) void*)(&lsA[buf*ASZ + base]), 16, 0, 0);
    }
  };
  auto stageB = [&](int buf, int stg) {
#pragma unroll
    for (int j = 0; j < (2*NBN)/4; ++j) {
      int inst = wv * ((2*NBN)/4) + j;
      int kk = inst / NBN;
      int nn = inst - kk*NBN;
      const char* src = (const char*)Bp + ((size_t)((stg*2 + kk)*NT + ntb*NBN + nn) * 64) * 16 + lane*16;
      __builtin_amdgcn_global_load_lds((const __attribute__((address_space(1))) void*)src,
          (__attribute__((address_space(3))) void*)(&lsB[buf*BSZ + inst*1024]), 16, 0, 0);
    }
  };
  auto compute = [&](int buf) {
#pragma unroll
    for (int kk = 0; kk < 2; ++kk) {
      bf16x8 af[RB];
#pragma unroll
      for (int rb = 0; rb < RB; ++rb) {
        int row = wrow + rb*16 + (lane & 15);
        int byte = (row*128 + kk*64 + (lane >> 4)*16) ^ ((row & 7) << 4);
        af[rb] = *reinterpret_cast<const bf16x8*>(&lsA[buf*ASZ + byte]);
      }
      bf16x8 bfr[4];
#pragma unroll
      for (int nt = 0; nt < 4; ++nt)
        bfr[nt] = *reinterpret_cast<const bf16x8*>(&lsB[buf*BSZ + ((kk*NBN + wntl + nt)*64 + lane)*16]);
#pragma unroll
      for (int nt = 0; nt < 4; ++nt)
#pragma unroll
        for (int rb = 0; rb < RB; ++rb)
          acc[rb][nt] = __builtin_amdgcn_mfma_f32_16x16x32_bf16(af[rb], bfr[nt], acc[rb][nt], 0, 0, 0);
    }
  };

  stageA(0, 0); stageB(0, 0);
  asm volatile("s_waitcnt vmcnt(0)" ::: "memory");
  __builtin_amdgcn_s_barrier();

  int cur = 0;
#pragma unroll 1
  for (int s = 0; s < NSTG; ++s) {
    if (DB == 2 && s + 1 < NSTG) { stageA(cur ^ 1, (s + 1) * 64); stageB(cur ^ 1, s + 1); }
    compute(cur);
    if (s + 1 < NSTG) {
      asm volatile("s_waitcnt vmcnt(0)" ::: "memory");
      __builtin_amdgcn_s_barrier();
      cur ^= 1;
    }
  }

  const int r = lane & 15, q = lane >> 4;
#pragma unroll
  for (int nt = 0; nt < 4; ++nt) {
    int col = ntb*BN + (wntl + nt)*16 + r;
    float bs = bias[col];
#pragma unroll
    for (int rb = 0; rb < RB; ++rb)
#pragma unroll
      for (int i = 0; i < 4; ++i) {
        int row = m0 + wrow + rb*16 + q*4 + i;
        float v = swishf(acc[rb][nt][i] + bs);
        if (SET63 && col == 63) v = 1.f;       // bias row for tp1-GEMM
        Out[(size_t)row*NP + col] = f2bf(v);
      }
  }
}

// ---------------- TP layer 1 as scaled GEMM: mbuf[e,n] = sum_u xj[e,u]*(x3[e,:]@W4N[u]) ----------------
__global__ __launch_bounds__(512, 4)
void tp1_gemm(const uint16_t* __restrict__ x3, const char* __restrict__ ws,
              const int* __restrict__ eidx, float* __restrict__ agg, int ec0)
{
  __shared__ __align__(16) uint16_t Wst[2][4096];   // 8KB per buffer
  __shared__ float xjs[64*32];
  __shared__ float mbuf[64*64];
  __shared__ float shls[64*3];
  __shared__ int   rowl[64];
  __shared__ int   coll[64];

  const float* hN  = (const float*)(ws + OFF_HN);
  const float* shl = (const float*)(ws + OFF_SHL);
  const char*  W4n = (const char*)(ws + OFF_W4N1);

  const int tid = threadIdx.x, lane = tid & 63, wv = tid >> 6;
  const int e0l = blockIdx.x * 64;
  const int eg0 = ec0 + e0l;
  const int r_ = lane & 15, q_ = lane >> 4;
  const int rowg = wv >> 1, colg = wv & 1;

  if (tid < 64) { rowl[tid] = eidx[eg0 + tid]; coll[tid] = eidx[E_EDGES + eg0 + tid]; }
  for (int i = tid; i < 192; i += 512) shls[i] = shl[(size_t)eg0*3 + i];
  __syncthreads();
  for (int i = tid; i < 64*32; i += 512) {
    int e = i >> 5, u = i & 31;
    xjs[i] = hN[(size_t)rowl[e]*32 + u];
  }

  // x3 A-fragments: rows rowg*16 + r_, k-chunks q_*8 (+32 for a1). Loaded once.
  bf16x8 a0, a1;
  {
    int row = e0l + rowg*16 + r_;
    const char* base = (const char*)x3 + (size_t)row*128 + q_*16;
    a0 = *reinterpret_cast<const bf16x8*>(base);
    a1 = *reinterpret_cast<const bf16x8*>(base + 64);
  }

  auto stageW = [&](int buf, int u) {
    const char* src = W4n + ((size_t)(u*8 + (tid >> 6))*64 + lane)*16;
    __builtin_amdgcn_global_load_lds((const __attribute__((address_space(1))) void*)src,
        (__attribute__((address_space(3))) void*)(&Wst[buf][(size_t)tid*8]), 16, 0, 0);
  };

  f32x4 zv = {0.f, 0.f, 0.f, 0.f};
  f32x4 accF[2];
  accF[0] = zv; accF[1] = zv;

  stageW(0, 0);
  __syncthreads();   // covers xjs writes + W stage

  int cur = 0;
#pragma unroll 1
  for (int u = 0; u < 30; ++u) {
    if (u + 1 < 30) stageW(cur ^ 1, u + 1);
    // B frags: tiles kk*4 + colg*2 + nt
    bf16x8 b00 = *reinterpret_cast<const bf16x8*>(&Wst[cur][(size_t)((0*4 + colg*2 + 0)*64 + lane)*8]);
    bf16x8 b01 = *reinterpret_cast<const bf16x8*>(&Wst[cur][(size_t)((0*4 + colg*2 + 1)*64 + lane)*8]);
    bf16x8 b10 = *reinterpret_cast<const bf16x8*>(&Wst[cur][(size_t)((1*4 + colg*2 + 0)*64 + lane)*8]);
    bf16x8 b11 = *reinterpret_cast<const bf16x8*>(&Wst[cur][(size_t)((1*4 + colg*2 + 1)*64 + lane)*8]);
    f32x4 t0 = __builtin_amdgcn_mfma_f32_16x16x32_bf16(a0, b00, zv, 0, 0, 0);
    t0 = __builtin_amdgcn_mfma_f32_16x16x32_bf16(a1, b10, t0, 0, 0, 0);
    f32x4 t1 = __builtin_amdgcn_mfma_f32_16x16x32_bf16(a0, b01, zv, 0, 0, 0);
    t1 = __builtin_amdgcn_mfma_f32_16x16x32_bf16(a1, b11, t1, 0, 0, 0);
#pragma unroll
    for (int i = 0; i < 4; ++i) {
      float xv = xjs[(rowg*16 + q_*4 + i)*32 + u];
      accF[0][i] += xv * t0[i];
      accF[1][i] += xv * t1[i];
    }
    if (u + 1 < 30) {
      asm volatile("s_waitcnt vmcnt(0)" ::: "memory");
      __builtin_amdgcn_s_barrier();
      cur ^= 1;
    }
  }

  // write mbuf (pitch 64): row = rowg*16+q*4+i, col = colg*32 + nt*16 + r
#pragma unroll
  for (int nt = 0; nt < 2; ++nt)
#pragma unroll
    for (int i = 0; i < 4; ++i)
      mbuf[(rowg*16 + q_*4 + i)*64 + colg*32 + nt*16 + r_] = accF[nt][i];
  __syncthreads();

  // scatter to agg
#pragma unroll 1
  for (int i = tid; i < 64*70; i += 512) {
    int e = i/70, c = i - e*70;
    float v;
    if (c < 40) v = mbuf[e*64 + c] * SH0C;
    else { int vv = (c - 40)/3, k = (c - 40) - vv*3; v = mbuf[e*64 + 40 + vv] * shls[e*3 + k]; }
    atomicAdd(&agg[(size_t)coll[e]*70 + c], v);
  }
}

// ---------------- TP layer 2 (atomic-free consumption, f32 w-tile) ----------------
__global__ __launch_bounds__(512, 2)
void tp2_kernel(const uint16_t* __restrict__ x3, const char* __restrict__ ws,
                const int* __restrict__ eidx, float* __restrict__ agg2, int ec0)
{
  constexpr int P2 = 67;
  __shared__ float wbuf2[64 * P2];
  __shared__ float xjs[64*30];
  __shared__ float xjv[64*30];
  __shared__ float Db[64*10];
  __shared__ float shls[64*3];
  __shared__ int   rowl[64];
  __shared__ int   coll[64];

  const float* h2  = (const float*)(ws + OFF_H2);
  const float* shl = (const float*)(ws + OFF_SHL);
  const float* b4p = (const float*)(ws + OFF_B4P2);
  const bf16x8* __restrict__ bv4 = (const bf16x8*)(ws + OFF_W4P2);

  const int tid = threadIdx.x, lane = tid & 63, wv = tid >> 6;
  const int e0l = blockIdx.x * 64;
  const int eg0 = ec0 + e0l;
  const int r_ = lane & 15, q_ = lane >> 4;

  if (tid < 64) { rowl[tid] = eidx[eg0 + tid]; coll[tid] = eidx[E_EDGES + eg0 + tid]; }
  for (int i = tid; i < 192; i += 512) shls[i] = shl[(size_t)eg0*3 + i];
  __syncthreads();
  for (int i = tid; i < 64*60; i += 512) {
    int e = i/60, u = i - e*60;
    float v = h2[(size_t)rowl[e]*64 + u];
    if (u < 30) xjs[e*30 + u] = v; else xjv[e*30 + (u - 30)] = v;
  }
  __syncthreads();
  for (int i = tid; i < 640; i += 512) {
    int e = i/10, v = i - e*10;
    float d = 0.f;
#pragma unroll
    for (int m = 0; m < 3; ++m) d += xjv[e*30 + v*3 + m] * shls[e*3 + m];
    Db[i] = d * INV_SQRT3;
  }

  const int rbase = (wv >> 2)*2, nt4 = wv & 3;
  bf16x8 a4[2][2];
#pragma unroll
  for (int kk = 0; kk < 2; ++kk)
#pragma unroll
    for (int rbi = 0; rbi < 2; ++rbi) {
      int row = e0l + (rbase + rbi)*16 + r_;
      a4[kk][rbi] = *reinterpret_cast<const bf16x8*>((const char*)x3 + (size_t)row*128 + kk*64 + q_*16);
    }
  f32x4 acc[2];
  f32x4 zv = {0.f, 0.f, 0.f, 0.f};
  acc[0] = zv; acc[1] = zv;
#pragma unroll
  for (int kk = 0; kk < 2; ++kk) {
    bf16x8 b4 = bv4[(size_t)(kk*4 + nt4)*64 + lane];
#pragma unroll
    for (int rbi = 0; rbi < 2; ++rbi)
      acc[rbi] = __builtin_amdgcn_mfma_f32_16x16x32_bf16(a4[kk][rbi], b4, acc[rbi], 0, 0, 0);
  }
  __syncthreads();
  {
    int cg = nt4*16 + r_;
    float bs = b4p[cg];
#pragma unroll
    for (int rbi = 0; rbi < 2; ++rbi)
#pragma unroll
      for (int i2 = 0; i2 < 4; ++i2) {
        int e = (rbase + rbi)*16 + q_*4 + i2;
        wbuf2[e*P2 + cg] = acc[rbi][i2] + bs;
      }
  }
  __syncthreads();

  if (tid < 64) {
    int e = tid;
    float m = 0.f, m2 = 0.f;
#pragma unroll
    for (int c = 0; c < 30; ++c) m += xjs[e*30 + c] * wbuf2[e*P2 + c];
#pragma unroll
    for (int vv = 0; vv < 10; ++vv) m2 += Db[e*10 + vv] * wbuf2[e*P2 + 30 + vv];
    atomicAdd(&agg2[coll[e]], m * (SH0C * INV_SQRT30) + m2 * INV_SQRT10);
  }
}

// ---------------- node kernels ----------------
__global__ void node_mid(char* ws, const float* __restrict__ si1w)
{
  int nid = blockIdx.x * blockDim.x + threadIdx.x;
  if (nid >= N_NODES) return;
  const float* hN  = (const float*)(ws + OFF_HN)  + (size_t)nid*32;
  const float* agg = (const float*)(ws + OFF_AGG) + (size_t)nid*70;
  float* h2        = (float*)(ws + OFF_H2)        + (size_t)nid*64;

  float hn[30];
#pragma unroll
  for (int u = 0; u < 30; ++u) hn[u] = hN[u];

  float h1[70];
#pragma unroll 1
  for (int v = 0; v < 40; ++v) {
    float s = 0.f;
#pragma unroll
    for (int u = 0; u < 30; ++u) s += hn[u] * si1w[u*40 + v];
    h1[v] = SQ2C * (s + agg[v]);
  }
#pragma unroll
  for (int c = 40; c < 70; ++c) h1[c] = agg[c];

#pragma unroll
  for (int u = 0; u < 30; ++u) h2[u] = swishf(h1[u]);
#pragma unroll
  for (int v = 0; v < 10; ++v) {
    float g = 1.f / (1.f + __expf(-h1[30 + v]));
#pragma unroll
    for (int k = 0; k < 3; ++k) h2[30 + v*3 + k] = h1[40 + v*3 + k] * g;
  }
}

__global__ void node_final(char* ws, const float* __restrict__ si2w, const int* __restrict__ batch)
{
  __shared__ float ls[NGRAPH];
  if (threadIdx.x < NGRAPH) ls[threadIdx.x] = 0.f;
  __syncthreads();
  int nid = blockIdx.x * blockDim.x + threadIdx.x;
  if (nid < N_NODES) {
    const float* h2   = (const float*)(ws + OFF_H2) + (size_t)nid*64;
    const float* agg2 = (const float*)(ws + OFF_AGG2);
    float s2 = 0.f;
#pragma unroll
    for (int u = 0; u < 30; ++u) s2 += h2[u] * si2w[u];
    float val = SQ2C * (s2 * INV_SQRT30 + agg2[nid]);
    atomicAdd(&ls[batch[nid]], val);
  }
  __syncthreads();
  if (threadIdx.x < NGRAPH)
    atomicAdd(((float*)(ws + OFF_GSUM)) + threadIdx.x, ls[threadIdx.x]);
}

__global__ void write_out(const char* ws, float* out)
{
  int g = threadIdx.x;
  if (g < NGRAPH) out[g] = ((const float*)(ws + OFF_GSUM))[g];
}

// ---------------- launch ----------------
extern "C" void kernel_launch(void* const* d_in, const int* in_sizes, int n_in,
                              void* d_out, int out_size, void* d_ws, size_t ws_size,
                              hipStream_t stream)
{
  const float* pos  = (const float*)d_in[0];
  const float* emb  = (const float*)d_in[1];
  const float* si1w = (const float*)d_in[2];
  const float* si2w = (const float*)d_in[3];
  const float* w1a = (const float*)d_in[4];  const float* b1a = (const float*)d_in[5];
  const float* w2a = (const float*)d_in[6];  const float* b2a = (const float*)d_in[7];
  const float* w3a = (const float*)d_in[8];  const float* b3a = (const float*)d_in[9];
  const float* w4a = (const float*)d_in[10]; const float* b4a = (const float*)d_in[11];
  const float* w1b = (const float*)d_in[12]; const float* b1b = (const float*)d_in[13];
  const float* w2b = (const float*)d_in[14]; const float* b2b = (const float*)d_in[15];
  const float* w3b = (const float*)d_in[16]; const float* b3b = (const float*)d_in[17];
  const float* w4b = (const float*)d_in[18]; const float* b4b = (const float*)d_in[19];
  const int* z     = (const int*)d_in[20];
  const int* eidx  = (const int*)d_in[21];
  const int* batch = (const int*)d_in[22];
  char* ws = (char*)d_ws;

  uint16_t* basis = (uint16_t*)(ws + OFF_BAS);
  float*    shl   = (float*)(ws + OFF_SHL);
  uint16_t* act1  = (uint16_t*)(ws + OFF_ACT1);
  uint16_t* act2  = (uint16_t*)(ws + OFF_ACT2);
  uint16_t* x3    = (uint16_t*)(ws + OFF_X3);

  hipMemsetAsync(ws + OFF_AGG, 0, OFF_ZEND - OFF_AGG, stream);

  prep_kernel<<<1437, 256, 0, stream>>>(w1a, w2a, w3a, w4a, w1b, w2b, w3b, w4b,
                                        b1a, b2a, b3a, b4a, b1b, b2b, b3b, b4b,
                                        emb, z, ws);
  edge_meta<<<E_EDGES/256, 256, 0, stream>>>(pos, eidx, basis, shl);

  // ---- layer 1 ----
  for (int c = 0; c < NCHUNK; ++c) {
    const uint16_t* basc = basis + (size_t)c*CHUNK*64;
    gemm_swish<64, 512, false><<<(CHUNK/128)*4, 256, 0, stream>>>(basc, (const uint16_t*)(ws + OFF_W1P1),
                                                                  (const float*)(ws + OFF_B1P1), act1);
    gemm_swish<512,512, false><<<(CHUNK/128)*4, 256, 0, stream>>>(act1, (const uint16_t*)(ws + OFF_W2P1),
                                                                  (const float*)(ws + OFF_B2P1), act2);
    gemm_swish<512, 64, true><<<(CHUNK/128),   256, 0, stream>>>(act2, (const uint16_t*)(ws + OFF_W3P1),
                                                                 (const float*)(ws + OFF_B3P1), x3);
    tp1_gemm<<<CHUNK/64, 512, 0, stream>>>(x3, ws, eidx, (float*)(ws + OFF_AGG), c*CHUNK);
  }

  node_mid<<<N_NODES/256, 256, 0, stream>>>(ws, si1w);

  // ---- layer 2 ----
  for (int c = 0; c < NCHUNK; ++c) {
    const uint16_t* basc = basis + (size_t)c*CHUNK*64;
    gemm_swish<64, 512, false><<<(CHUNK/128)*4, 256, 0, stream>>>(basc, (const uint16_t*)(ws + OFF_W1P2),
                                                                  (const float*)(ws + OFF_B1P2), act1);
    gemm_swish<512,512, false><<<(CHUNK/128)*4, 256, 0, stream>>>(act1, (const uint16_t*)(ws + OFF_W2P2),
                                                                  (const float*)(ws + OFF_B2P2), act2);
    gemm_swish<512, 64, true><<<(CHUNK/128),   256, 0, stream>>>(act2, (const uint16_t*)(ws + OFF_W3P2),
                                                                 (const float*)(ws + OFF_B3P2), x3);
    tp2_kernel<<<CHUNK/64, 512, 0, stream>>>(x3, ws, eidx, (float*)(ws + OFF_AGG2), c*CHUNK);
  }

  node_final<<<N_NODES/256, 256, 0, stream>>>(ws, si2w, batch);
  write_out<<<1, 64, 0, stream>>>(ws, (float*)d_out);
}

// Round 16
// 686.034 us; speedup vs baseline: 1.5386x; 1.1759x over previous
//
#include <hip/hip_runtime.h>
#include <stdint.h>

typedef __attribute__((ext_vector_type(8))) short bf16x8;
typedef __attribute__((ext_vector_type(4))) float f32x4;

#define N_NODES 8192
#define E_EDGES 163840
#define NGRAPH  32

#define INV_SQRT30 0.18257419f
#define SH0C       0.22360680f   /* 1/sqrt(20) */
#define SQRT3C     1.73205081f
#define INV_SQRT3  0.57735027f
#define INV_SQRT10 0.31622777f
#define SQ2C       0.70710678f

// ---------------- fixed workspace layout (bytes) ----------------
enum : unsigned {
  OFF_W1P1 = 0u,       OFF_W2P1 = 65536u,   OFF_W3P1 = 589824u,  OFF_W4P1 = 655360u,
  OFF_W1P2 = 851968u,  OFF_W2P2 = 917504u,  OFF_W3P2 = 1441792u, OFF_W4P2 = 1507328u,
  OFF_B1P1 = 1515520u, OFF_B2P1 = 1517568u, OFF_B3P1 = 1519616u, OFF_B4P1 = 1519872u,
  OFF_B1P2 = 1526016u, OFF_B2P2 = 1528064u, OFF_B3P2 = 1530112u, OFF_B4P2 = 1530368u,
  OFF_HN   = 1530624u, // [8192][32] f32
  OFF_H2   = 2579200u, // [8192][64] f32
  OFF_AGG  = 4676352u, // [8192][70] f32
  OFF_AGG2 = 6970112u, // [8192] f32
  OFF_GSUM = 7002880u, // [32] f32
  OFF_ZEND = 7003008u,
  OFF_SHL  = 7003136u,  // [E][3] f32
  OFF_BAS  = 8969216u,  // [E][64] bf16 (linear)
  OFF_W4N1 = 29940736u, // 30 x 8 x 1KB
  OFF_DYN  = 30186496u  // dynamic region: act1 | act2 | x3 (runtime-sized chunks)
};

__device__ __forceinline__ uint16_t f2bf(float f){
  union { float f; uint32_t u; } v; v.f = f;
  uint32_t r = v.u + 0x7fffu + ((v.u >> 16) & 1u);
  return (uint16_t)(r >> 16);
}
__device__ __forceinline__ float swishf(float x){ return x / (1.f + __expf(-x)); }

// ---------------- weight pre-pack (f32 src -> bf16 MFMA B-fragment order) ----------------
__device__ __forceinline__ void pack_mat(const float* __restrict__ src, int K, int N, int NP,
                                         uint16_t* __restrict__ dst, int t)
{
  int lane = t & 63;
  int tile = t >> 6;
  int NT = NP >> 4;
  int nn = tile % NT, kk = tile / NT;
  int k0 = kk*32 + ((lane >> 4) << 3);
  int n  = nn*16 + (lane & 15);
  union { short s[8]; bf16x8 v; } tmp;
#pragma unroll
  for (int b = 0; b < 8; ++b) {
    int k = k0 + b;
    tmp.s[b] = (k < K && n < N) ? (short)f2bf(src[(size_t)k*N + n]) : (short)0;
  }
  *reinterpret_cast<bf16x8*>(dst + (size_t)t*8) = tmp.v;
}

// W4' pack for tp1-as-GEMM: step u (0..29), tile j=kk*4+nn; rows k (x3 cols, 63=bias), cols n (0..49 real)
__device__ __forceinline__ void pack_w4n(const float* __restrict__ w4, const float* __restrict__ b4,
                                         uint16_t* __restrict__ dst, int t)
{
  int lane = t & 63;
  int tile = t >> 6;           // 0..239
  int u = tile >> 3, j = tile & 7;
  int kk = j >> 2, nn = j & 3;
  int k0 = kk*32 + ((lane >> 4) << 3);
  int n  = nn*16 + (lane & 15);
  union { short s[8]; bf16x8 v; } tmp;
#pragma unroll
  for (int b = 0; b < 8; ++b) {
    int k = k0 + b;
    float val = 0.f;
    if (n < 50) {
      int cg = (n < 40) ? (u*40 + n) : (1200 + u*10 + (n - 40));
      if (k < 50) val = w4[(size_t)k*1500 + cg];
      else if (k == 63) val = b4[cg];
    }
    tmp.s[b] = (short)f2bf(val);
  }
  *reinterpret_cast<bf16x8*>(dst + (size_t)t*8) = tmp.v;
}

__global__ void prep_kernel(const float* w1a, const float* w2a, const float* w3a, const float* w4a,
                            const float* w1b, const float* w2b, const float* w3b, const float* w4b,
                            const float* b1a, const float* b2a, const float* b3a, const float* b4a,
                            const float* b1b, const float* b2b, const float* b3b, const float* b4b,
                            const float* emb, const int* z, char* ws)
{
  int t = blockIdx.x * 256 + threadIdx.x;
  if      (t < 4096)   pack_mat(w1a, 40, 500, 512,  (uint16_t*)(ws + OFF_W1P1), t);
  else if (t < 36864)  pack_mat(w2a, 500,500, 512,  (uint16_t*)(ws + OFF_W2P1), t - 4096);
  else if (t < 40960)  pack_mat(w3a, 500, 50, 64,   (uint16_t*)(ws + OFF_W3P1), t - 36864);
  else if (t < 45056)  { /* spare */ }
  else if (t < 49152)  pack_mat(w1b, 40, 500, 512,  (uint16_t*)(ws + OFF_W1P2), t - 45056);
  else if (t < 81920)  pack_mat(w2b, 500,500, 512,  (uint16_t*)(ws + OFF_W2P2), t - 49152);
  else if (t < 86016)  pack_mat(w3b, 500, 50, 64,   (uint16_t*)(ws + OFF_W3P2), t - 81920);
  else if (t < 86528)  pack_mat(w4b, 50,  40, 64,   (uint16_t*)(ws + OFF_W4P2), t - 86016);
  else if (t < 90304) {
    int loc = t - 86528;
    const float* src; float* dst; int realN;
    if      (loc < 512)  { src=b1a; dst=(float*)(ws+OFF_B1P1); realN=500; }
    else if (loc < 1024) { src=b2a; dst=(float*)(ws+OFF_B2P1); realN=500;  loc -= 512;  }
    else if (loc < 1088) { src=b3a; dst=(float*)(ws+OFF_B3P1); realN=50;   loc -= 1024; }
    else if (loc < 2624) { src=b4a; dst=(float*)(ws+OFF_B4P1); realN=1500; loc -= 1088; }
    else if (loc < 3136) { src=b1b; dst=(float*)(ws+OFF_B1P2); realN=500;  loc -= 2624; }
    else if (loc < 3648) { src=b2b; dst=(float*)(ws+OFF_B2P2); realN=500;  loc -= 3136; }
    else if (loc < 3712) { src=b3b; dst=(float*)(ws+OFF_B3P2); realN=50;   loc -= 3648; }
    else                 { src=b4b; dst=(float*)(ws+OFF_B4P2); realN=40;   loc -= 3712; }
    dst[loc] = (loc < realN) ? src[loc] : 0.f;
  }
  else if (t < 352448) {
    int i = t - 90304;
    int n = i >> 5, u = i & 31;
    float v = 0.f;
    if (u < 30) v = emb[(size_t)z[n]*30 + u] * INV_SQRT30;
    ((float*)(ws + OFF_HN))[i] = v;
  }
  else if (t < 367808) {
    pack_w4n(w4a, b4a, (uint16_t*)(ws + OFF_W4N1), t - 352448);
  }
}

// ---------------- edge meta ----------------
__global__ void edge_meta(const float* __restrict__ pos, const int* __restrict__ eidx,
                          uint16_t* __restrict__ basis, float* __restrict__ shl)
{
  int e = blockIdx.x * 256 + threadIdx.x;
  if (e >= E_EDGES) return;
  int rn = eidx[e], cn = eidx[E_EDGES + e];
  float ax = pos[rn*3+0] - pos[cn*3+0];
  float ay = pos[rn*3+1] - pos[cn*3+1];
  float az = pos[rn*3+2] - pos[cn*3+2];
  float rr = sqrtf(ax*ax + ay*ay + az*az + 1e-12f);
  float s = SQRT3C * SH0C / rr;
  shl[e*3+0] = ax*s; shl[e*3+1] = ay*s; shl[e*3+2] = az*s;
#pragma unroll
  for (int j = 0; j < 8; ++j) {
    union { short s[8]; bf16x8 v; } tmp;
#pragma unroll
    for (int b = 0; b < 8; ++b) {
      int c = j*8 + b;
      float vv = 0.f;
      if (c < 40) { float t = rr*3.9f - (float)c; vv = __expf(-t*t); }
      tmp.s[b] = (short)f2bf(vv);
    }
    *reinterpret_cast<bf16x8*>(basis + (size_t)e*64 + j*8) = tmp.v;
  }
}

// ---------------- batched GEMM + swish (2-phase pipeline, hoisted addressing) ----------------
template<int KP, int NP, bool SET63>
__global__ __launch_bounds__(256)
void gemm_swish(const uint16_t* __restrict__ A, const uint16_t* __restrict__ Bp,
                const float* __restrict__ bias, uint16_t* __restrict__ Out)
{
  constexpr int BN   = (NP == 512) ? 128 : 64;
  constexpr int NBN  = BN / 16;
  constexpr int NT   = NP / 16;
  constexpr int NSTG = KP / 64;
  constexpr int DB   = (NSTG > 1) ? 2 : 1;
  constexpr int RB   = (NP == 512) ? 4 : 2;
  constexpr int ASZ  = 16384;
  constexpr int BSZ  = NBN * 2048;
  constexpr int NBJ  = (2*NBN)/4;

  __shared__ __align__(16) char lsA[DB * ASZ];
  __shared__ __align__(16) char lsB[DB * BSZ];

  const int tid = threadIdx.x, lane = tid & 63, wv = tid >> 6;
  int mt, ntb;
  if (NP == 512) {
    int b = blockIdx.x;
    int xcd = b & 7, slot = b >> 3;
    ntb = slot & 3;
    mt  = (slot >> 2) * 8 + xcd;      // grid = mts*4, mts % 8 == 0
  } else { ntb = 0; mt = blockIdx.x; }
  const int m0  = mt * 128;
  const int wrow = (NP == 512) ? (wv >> 1) * 64 : wv * 32;
  const int wntl = (NP == 512) ? (wv & 1) * 4 : 0;

  // hoisted global src pointers (per-thread constant; stage adds scalar offset)
  const char* srcA[4];
  int dstA[4];
#pragma unroll
  for (int j = 0; j < 4; ++j) {
    int base = (wv*4 + j) * 1024;
    int d = base + lane*16;
    int row = d >> 7;
    int colb = (d & 127) ^ ((row & 7) << 4);
    srcA[j] = (const char*)A + (size_t)(m0 + row)*(KP*2) + colb;
    dstA[j] = base;
  }
  const char* srcB[NBJ];
  int dstB[NBJ];
#pragma unroll
  for (int j = 0; j < NBJ; ++j) {
    int inst = wv * NBJ + j;
    int kk = inst / NBN;
    int nn = inst - kk*NBN;
    srcB[j] = (const char*)Bp + ((size_t)(kk*NT + ntb*NBN + nn) * 64) * 16 + lane*16;
    dstB[j] = inst*1024;
  }
  // hoisted LDS read bases
  const int r = lane & 15, q = lane >> 4;
  const int aoff = wrow*128 + r*128 + ((q*16) ^ ((lane & 7) << 4));
  const int boff = lane*16 + wntl*1024;

  f32x4 acc[RB][4];
  f32x4 zv = {0.f, 0.f, 0.f, 0.f};
#pragma unroll
  for (int a = 0; a < RB; ++a)
#pragma unroll
    for (int b = 0; b < 4; ++b) acc[a][b] = zv;

  auto stageA = [&](int buf, int s) {
#pragma unroll
    for (int j = 0; j < 4; ++j)
      __builtin_amdgcn_global_load_lds((const __attribute__((address_space(1))) void*)(srcA[j] + (size_t)s*128),
          (__attribute__((address_space(3))) void*)(&lsA[buf*ASZ + dstA[j]]), 16, 0, 0);
  };
  auto stageB = [&](int buf, int s) {
#pragma unroll
    for (int j = 0; j < NBJ; ++j)
      __builtin_amdgcn_global_load_lds((const __attribute__((address_space(1))) void*)(srcB[j] + (size_t)s*(2*NT)*1024),
          (__attribute__((address_space(3))) void*)(&lsB[buf*BSZ + dstB[j]]), 16, 0, 0);
  };
  auto compute = [&](int buf) {
    const char* bA0 = lsA + buf*ASZ + aoff;
    const char* bA1 = lsA + buf*ASZ + (aoff ^ 64);
    const char* bB  = lsB + buf*BSZ + boff;
#pragma unroll
    for (int kk = 0; kk < 2; ++kk) {
      const char* bA = kk ? bA1 : bA0;
      bf16x8 af[RB];
#pragma unroll
      for (int rb = 0; rb < RB; ++rb)
        af[rb] = *reinterpret_cast<const bf16x8*>(bA + rb*2048);
      bf16x8 bfr[4];
#pragma unroll
      for (int nt = 0; nt < 4; ++nt)
        bfr[nt] = *reinterpret_cast<const bf16x8*>(bB + (kk*NBN + nt)*1024);
#pragma unroll
      for (int nt = 0; nt < 4; ++nt)
#pragma unroll
        for (int rb = 0; rb < RB; ++rb)
          acc[rb][nt] = __builtin_amdgcn_mfma_f32_16x16x32_bf16(af[rb], bfr[nt], acc[rb][nt], 0, 0, 0);
    }
  };

  stageA(0, 0); stageB(0, 0);
  asm volatile("s_waitcnt vmcnt(0)" ::: "memory");
  __builtin_amdgcn_s_barrier();

  int cur = 0;
#pragma unroll 1
  for (int s = 0; s < NSTG; ++s) {
    if (DB == 2 && s + 1 < NSTG) { stageA(cur ^ 1, s + 1); stageB(cur ^ 1, s + 1); }
    compute(cur);
    if (s + 1 < NSTG) {
      asm volatile("s_waitcnt vmcnt(0)" ::: "memory");
      __builtin_amdgcn_s_barrier();
      cur ^= 1;
    }
  }

#pragma unroll
  for (int nt = 0; nt < 4; ++nt) {
    int col = ntb*BN + (wntl + nt)*16 + r;
    float bs = bias[col];
#pragma unroll
    for (int rb = 0; rb < RB; ++rb)
#pragma unroll
      for (int i = 0; i < 4; ++i) {
        int row = m0 + wrow + rb*16 + q*4 + i;
        float v = swishf(acc[rb][nt][i] + bs);
        if (SET63 && col == 63) v = 1.f;       // bias row for tp1-GEMM
        Out[(size_t)row*NP + col] = f2bf(v);
      }
  }
}

// ---------------- TP layer 1 as scaled GEMM ----------------
__global__ __launch_bounds__(512, 4)
void tp1_gemm(const uint16_t* __restrict__ x3, const char* __restrict__ ws,
              const int* __restrict__ eidx, float* __restrict__ agg, int ec0)
{
  __shared__ __align__(16) uint16_t Wst[2][4096];   // 8KB per buffer
  __shared__ float xjs[64*32];
  __shared__ float mbuf[64*64];
  __shared__ float shls[64*3];
  __shared__ int   rowl[64];
  __shared__ int   coll[64];

  const float* hN  = (const float*)(ws + OFF_HN);
  const float* shl = (const float*)(ws + OFF_SHL);
  const char*  W4n = (const char*)(ws + OFF_W4N1);

  const int tid = threadIdx.x, lane = tid & 63, wv = tid >> 6;
  const int e0l = blockIdx.x * 64;
  const int eg0 = ec0 + e0l;
  const int r_ = lane & 15, q_ = lane >> 4;
  const int rowg = wv >> 1, colg = wv & 1;

  if (tid < 64) { rowl[tid] = eidx[eg0 + tid]; coll[tid] = eidx[E_EDGES + eg0 + tid]; }
  for (int i = tid; i < 192; i += 512) shls[i] = shl[(size_t)eg0*3 + i];
  __syncthreads();
  for (int i = tid; i < 64*32; i += 512) {
    int e = i >> 5, u = i & 31;
    xjs[i] = hN[(size_t)rowl[e]*32 + u];
  }

  bf16x8 a0, a1;
  {
    int row = e0l + rowg*16 + r_;
    const char* base = (const char*)x3 + (size_t)row*128 + q_*16;
    a0 = *reinterpret_cast<const bf16x8*>(base);
    a1 = *reinterpret_cast<const bf16x8*>(base + 64);
  }

  const char* srcW = W4n + ((size_t)(tid >> 6)*64 + lane)*16;
  auto stageW = [&](int buf, int u) {
    __builtin_amdgcn_global_load_lds((const __attribute__((address_space(1))) void*)(srcW + (size_t)u*8192),
        (__attribute__((address_space(3))) void*)(&Wst[buf][(size_t)tid*8]), 16, 0, 0);
  };

  f32x4 zv = {0.f, 0.f, 0.f, 0.f};
  f32x4 accF[2];
  accF[0] = zv; accF[1] = zv;

  stageW(0, 0);
  __syncthreads();   // covers xjs writes + W stage

  const char* wb0 = (const char*)&Wst[0][0] + ((size_t)(colg*2)*64 + lane)*16;
  const char* wb1 = (const char*)&Wst[1][0] + ((size_t)(colg*2)*64 + lane)*16;

  int cur = 0;
#pragma unroll 1
  for (int u = 0; u < 30; ++u) {
    if (u + 1 < 30) stageW(cur ^ 1, u + 1);
    const char* wb = cur ? wb1 : wb0;
    bf16x8 b00 = *reinterpret_cast<const bf16x8*>(wb);
    bf16x8 b01 = *reinterpret_cast<const bf16x8*>(wb + 1024);
    bf16x8 b10 = *reinterpret_cast<const bf16x8*>(wb + 4096);
    bf16x8 b11 = *reinterpret_cast<const bf16x8*>(wb + 5120);
    f32x4 t0 = __builtin_amdgcn_mfma_f32_16x16x32_bf16(a0, b00, zv, 0, 0, 0);
    t0 = __builtin_amdgcn_mfma_f32_16x16x32_bf16(a1, b10, t0, 0, 0, 0);
    f32x4 t1 = __builtin_amdgcn_mfma_f32_16x16x32_bf16(a0, b01, zv, 0, 0, 0);
    t1 = __builtin_amdgcn_mfma_f32_16x16x32_bf16(a1, b11, t1, 0, 0, 0);
#pragma unroll
    for (int i = 0; i < 4; ++i) {
      float xv = xjs[(rowg*16 + q_*4 + i)*32 + u];
      accF[0][i] += xv * t0[i];
      accF[1][i] += xv * t1[i];
    }
    if (u + 1 < 30) {
      asm volatile("s_waitcnt vmcnt(0)" ::: "memory");
      __builtin_amdgcn_s_barrier();
      cur ^= 1;
    }
  }

#pragma unroll
  for (int nt = 0; nt < 2; ++nt)
#pragma unroll
    for (int i = 0; i < 4; ++i)
      mbuf[(rowg*16 + q_*4 + i)*64 + colg*32 + nt*16 + r_] = accF[nt][i];
  __syncthreads();

#pragma unroll 1
  for (int i = tid; i < 64*70; i += 512) {
    int e = i/70, c = i - e*70;
    float v;
    if (c < 40) v = mbuf[e*64 + c] * SH0C;
    else { int vv = (c - 40)/3, k = (c - 40) - vv*3; v = mbuf[e*64 + 40 + vv] * shls[e*3 + k]; }
    atomicAdd(&agg[(size_t)coll[e]*70 + c], v);
  }
}

// ---------------- TP layer 2 (atomic-free consumption, f32 w-tile) ----------------
__global__ __launch_bounds__(512, 2)
void tp2_kernel(const uint16_t* __restrict__ x3, const char* __restrict__ ws,
                const int* __restrict__ eidx, float* __restrict__ agg2, int ec0)
{
  constexpr int P2 = 67;
  __shared__ float wbuf2[64 * P2];
  __shared__ float xjs[64*30];
  __shared__ float xjv[64*30];
  __shared__ float Db[64*10];
  __shared__ float shls[64*3];
  __shared__ int   rowl[64];
  __shared__ int   coll[64];

  const float* h2  = (const float*)(ws + OFF_H2);
  const float* shl = (const float*)(ws + OFF_SHL);
  const float* b4p = (const float*)(ws + OFF_B4P2);
  const bf16x8* __restrict__ bv4 = (const bf16x8*)(ws + OFF_W4P2);

  const int tid = threadIdx.x, lane = tid & 63, wv = tid >> 6;
  const int e0l = blockIdx.x * 64;
  const int eg0 = ec0 + e0l;
  const int r_ = lane & 15, q_ = lane >> 4;

  if (tid < 64) { rowl[tid] = eidx[eg0 + tid]; coll[tid] = eidx[E_EDGES + eg0 + tid]; }
  for (int i = tid; i < 192; i += 512) shls[i] = shl[(size_t)eg0*3 + i];
  __syncthreads();
  for (int i = tid; i < 64*60; i += 512) {
    int e = i/60, u = i - e*60;
    float v = h2[(size_t)rowl[e]*64 + u];
    if (u < 30) xjs[e*30 + u] = v; else xjv[e*30 + (u - 30)] = v;
  }
  __syncthreads();
  for (int i = tid; i < 640; i += 512) {
    int e = i/10, v = i - e*10;
    float d = 0.f;
#pragma unroll
    for (int m = 0; m < 3; ++m) d += xjv[e*30 + v*3 + m] * shls[e*3 + m];
    Db[i] = d * INV_SQRT3;
  }

  const int rbase = (wv >> 2)*2, nt4 = wv & 3;
  bf16x8 a4[2][2];
#pragma unroll
  for (int kk = 0; kk < 2; ++kk)
#pragma unroll
    for (int rbi = 0; rbi < 2; ++rbi) {
      int row = e0l + (rbase + rbi)*16 + r_;
      a4[kk][rbi] = *reinterpret_cast<const bf16x8*>((const char*)x3 + (size_t)row*128 + kk*64 + q_*16);
    }
  f32x4 acc[2];
  f32x4 zv = {0.f, 0.f, 0.f, 0.f};
  acc[0] = zv; acc[1] = zv;
#pragma unroll
  for (int kk = 0; kk < 2; ++kk) {
    bf16x8 b4 = bv4[(size_t)(kk*4 + nt4)*64 + lane];
#pragma unroll
    for (int rbi = 0; rbi < 2; ++rbi)
      acc[rbi] = __builtin_amdgcn_mfma_f32_16x16x32_bf16(a4[kk][rbi], b4, acc[rbi], 0, 0, 0);
  }
  __syncthreads();
  {
    int cg = nt4*16 + r_;
    float bs = b4p[cg];
#pragma unroll
    for (int rbi = 0; rbi < 2; ++rbi)
#pragma unroll
      for (int i2 = 0; i2 < 4; ++i2) {
        int e = (rbase + rbi)*16 + q_*4 + i2;
        wbuf2[e*P2 + cg] = acc[rbi][i2] + bs;
      }
  }
  __syncthreads();

  if (tid < 64) {
    int e = tid;
    float m = 0.f, m2 = 0.f;
#pragma unroll
    for (int c = 0; c < 30; ++c) m += xjs[e*30 + c] * wbuf2[e*P2 + c];
#pragma unroll
    for (int vv = 0; vv < 10; ++vv) m2 += Db[e*10 + vv] * wbuf2[e*P2 + 30 + vv];
    atomicAdd(&agg2[coll[e]], m * (SH0C * INV_SQRT30) + m2 * INV_SQRT10);
  }
}

// ---------------- node kernels ----------------
__global__ void node_mid(char* ws, const float* __restrict__ si1w)
{
  int nid = blockIdx.x * blockDim.x + threadIdx.x;
  if (nid >= N_NODES) return;
  const float* hN  = (const float*)(ws + OFF_HN)  + (size_t)nid*32;
  const float* agg = (const float*)(ws + OFF_AGG) + (size_t)nid*70;
  float* h2        = (float*)(ws + OFF_H2)        + (size_t)nid*64;

  float hn[30];
#pragma unroll
  for (int u = 0; u < 30; ++u) hn[u] = hN[u];

  float h1[70];
#pragma unroll 1
  for (int v = 0; v < 40; ++v) {
    float s = 0.f;
#pragma unroll
    for (int u = 0; u < 30; ++u) s += hn[u] * si1w[u*40 + v];
    h1[v] = SQ2C * (s + agg[v]);
  }
#pragma unroll
  for (int c = 40; c < 70; ++c) h1[c] = agg[c];

#pragma unroll
  for (int u = 0; u < 30; ++u) h2[u] = swishf(h1[u]);
#pragma unroll
  for (int v = 0; v < 10; ++v) {
    float g = 1.f / (1.f + __expf(-h1[30 + v]));
#pragma unroll
    for (int k = 0; k < 3; ++k) h2[30 + v*3 + k] = h1[40 + v*3 + k] * g;
  }
}

__global__ void node_final(char* ws, const float* __restrict__ si2w, const int* __restrict__ batch)
{
  __shared__ float ls[NGRAPH];
  if (threadIdx.x < NGRAPH) ls[threadIdx.x] = 0.f;
  __syncthreads();
  int nid = blockIdx.x * blockDim.x + threadIdx.x;
  if (nid < N_NODES) {
    const float* h2   = (const float*)(ws + OFF_H2) + (size_t)nid*64;
    const float* agg2 = (const float*)(ws + OFF_AGG2);
    float s2 = 0.f;
#pragma unroll
    for (int u = 0; u < 30; ++u) s2 += h2[u] * si2w[u];
    float val = SQ2C * (s2 * INV_SQRT30 + agg2[nid]);
    atomicAdd(&ls[batch[nid]], val);
  }
  __syncthreads();
  if (threadIdx.x < NGRAPH)
    atomicAdd(((float*)(ws + OFF_GSUM)) + threadIdx.x, ls[threadIdx.x]);
}

__global__ void write_out(const char* ws, float* out)
{
  int g = threadIdx.x;
  if (g < NGRAPH) out[g] = ((const float*)(ws + OFF_GSUM))[g];
}

// ---------------- launch ----------------
extern "C" void kernel_launch(void* const* d_in, const int* in_sizes, int n_in,
                              void* d_out, int out_size, void* d_ws, size_t ws_size,
                              hipStream_t stream)
{
  const float* pos  = (const float*)d_in[0];
  const float* emb  = (const float*)d_in[1];
  const float* si1w = (const float*)d_in[2];
  const float* si2w = (const float*)d_in[3];
  const float* w1a = (const float*)d_in[4];  const float* b1a = (const float*)d_in[5];
  const float* w2a = (const float*)d_in[6];  const float* b2a = (const float*)d_in[7];
  const float* w3a = (const float*)d_in[8];  const float* b3a = (const float*)d_in[9];
  const float* w4a = (const float*)d_in[10]; const float* b4a = (const float*)d_in[11];
  const float* w1b = (const float*)d_in[12]; const float* b1b = (const float*)d_in[13];
  const float* w2b = (const float*)d_in[14]; const float* b2b = (const float*)d_in[15];
  const float* w3b = (const float*)d_in[16]; const float* b3b = (const float*)d_in[17];
  const float* w4b = (const float*)d_in[18]; const float* b4b = (const float*)d_in[19];
  const int* z     = (const int*)d_in[20];
  const int* eidx  = (const int*)d_in[21];
  const int* batch = (const int*)d_in[22];
  char* ws = (char*)d_ws;

  uint16_t* basis = (uint16_t*)(ws + OFF_BAS);
  float*    shl   = (float*)(ws + OFF_SHL);

  // runtime-sized chunking: act1 + act2 + x3 = 2176 B/edge in the dynamic region
  const size_t per_edge = 2176;
  int chunk = 32768;
  if      (ws_size >= OFF_DYN + (size_t)163840*per_edge) chunk = 163840;
  else if (ws_size >= OFF_DYN + (size_t)81920 *per_edge) chunk = 81920;
  else if (ws_size >= OFF_DYN + (size_t)40960 *per_edge) chunk = 40960;
  const int nchunk = E_EDGES / chunk;

  uint16_t* act1 = (uint16_t*)(ws + OFF_DYN);
  uint16_t* act2 = act1 + (size_t)chunk*512;
  uint16_t* x3   = act2 + (size_t)chunk*512;

  hipMemsetAsync(ws + OFF_AGG, 0, OFF_ZEND - OFF_AGG, stream);

  prep_kernel<<<1437, 256, 0, stream>>>(w1a, w2a, w3a, w4a, w1b, w2b, w3b, w4b,
                                        b1a, b2a, b3a, b4a, b1b, b2b, b3b, b4b,
                                        emb, z, ws);
  edge_meta<<<E_EDGES/256, 256, 0, stream>>>(pos, eidx, basis, shl);

  // ---- layer 1 ----
  for (int c = 0; c < nchunk; ++c) {
    const uint16_t* basc = basis + (size_t)c*chunk*64;
    gemm_swish<64, 512, false><<<(chunk/128)*4, 256, 0, stream>>>(basc, (const uint16_t*)(ws + OFF_W1P1),
                                                                  (const float*)(ws + OFF_B1P1), act1);
    gemm_swish<512,512, false><<<(chunk/128)*4, 256, 0, stream>>>(act1, (const uint16_t*)(ws + OFF_W2P1),
                                                                  (const float*)(ws + OFF_B2P1), act2);
    gemm_swish<512, 64, true><<<(chunk/128),   256, 0, stream>>>(act2, (const uint16_t*)(ws + OFF_W3P1),
                                                                 (const float*)(ws + OFF_B3P1), x3);
    tp1_gemm<<<chunk/64, 512, 0, stream>>>(x3, ws, eidx, (float*)(ws + OFF_AGG), c*chunk);
  }

  node_mid<<<N_NODES/256, 256, 0, stream>>>(ws, si1w);

  // ---- layer 2 ----
  for (int c = 0; c < nchunk; ++c) {
    const uint16_t* basc = basis + (size_t)c*chunk*64;
    gemm_swish<64, 512, false><<<(chunk/128)*4, 256, 0, stream>>>(basc, (const uint16_t*)(ws + OFF_W1P2),
                                                                  (const float*)(ws + OFF_B1P2), act1);
    gemm_swish<512,512, false><<<(chunk/128)*4, 256, 0, stream>>>(act1, (const uint16_t*)(ws + OFF_W2P2),
                                                                  (const float*)(ws + OFF_B2P2), act2);
    gemm_swish<512, 64, true><<<(chunk/128),   256, 0, stream>>>(act2, (const uint16_t*)(ws + OFF_W3P2),
                                                                 (const float*)(ws + OFF_B3P2), x3);
    tp2_kernel<<<chunk/64, 512, 0, stream>>>(x3, ws, eidx, (float*)(ws + OFF_AGG2), c*chunk);
  }

  node_final<<<N_NODES/256, 256, 0, stream>>>(ws, si2w, batch);
  write_out<<<1, 64, 0, stream>>>(ws, (float*)d_out);
}

// Round 17
// 674.584 us; speedup vs baseline: 1.5648x; 1.0170x over previous
//
#include <hip/hip_runtime.h>
#include <stdint.h>

typedef __attribute__((ext_vector_type(8))) short bf16x8;
typedef __attribute__((ext_vector_type(4))) float f32x4;

#define N_NODES 8192
#define E_EDGES 163840
#define NGRAPH  32

#define INV_SQRT30 0.18257419f
#define SH0C       0.22360680f   /* 1/sqrt(20) */
#define SQRT3C     1.73205081f
#define INV_SQRT3  0.57735027f
#define INV_SQRT10 0.31622777f
#define SQ2C       0.70710678f

// ---------------- workspace layout (bytes) ----------------
enum : unsigned {
  OFF_W1P1 = 0u,       OFF_W2P1 = 65536u,   OFF_W3P1 = 589824u,  OFF_W4P1 = 655360u,
  OFF_W1P2 = 851968u,  OFF_W2P2 = 917504u,  OFF_W3P2 = 1441792u, OFF_W4P2 = 1507328u,
  OFF_B1P1 = 1515520u, OFF_B2P1 = 1517568u, OFF_B3P1 = 1519616u, OFF_B4P1 = 1519872u,
  OFF_B1P2 = 1526016u, OFF_B2P2 = 1528064u, OFF_B3P2 = 1530112u, OFF_B4P2 = 1530368u,
  OFF_HN   = 1530624u, // [8192][32] f32
  OFF_H2   = 2579200u, // [8192][64] f32
  OFF_AGG  = 4676352u, // [8192][70] f32
  OFF_AGG2 = 6970112u, // [8192] f32
  OFF_GSUM = 7002880u, // [32] f32
  OFF_ZEND = 7003008u,
  OFF_SHL  = 7003136u,  // [E][3] f32
  OFF_BAS  = 8969216u,  // [E][64] bf16 (linear)
  OFF_W4N1 = 29940736u, // 30 x 8 x 1KB
  OFF_X3   = 30186496u  // [E][64] bf16
};

__device__ __forceinline__ uint16_t f2bf(float f){
  union { float f; uint32_t u; } v; v.f = f;
  uint32_t r = v.u + 0x7fffu + ((v.u >> 16) & 1u);
  return (uint16_t)(r >> 16);
}
__device__ __forceinline__ float swishf(float x){ return x / (1.f + __expf(-x)); }

// ---------------- weight pre-pack (f32 src -> bf16 MFMA B-fragment order) ----------------
__device__ __forceinline__ void pack_mat(const float* __restrict__ src, int K, int N, int NP,
                                         uint16_t* __restrict__ dst, int t)
{
  int lane = t & 63;
  int tile = t >> 6;
  int NT = NP >> 4;
  int nn = tile % NT, kk = tile / NT;
  int k0 = kk*32 + ((lane >> 4) << 3);
  int n  = nn*16 + (lane & 15);
  union { short s[8]; bf16x8 v; } tmp;
#pragma unroll
  for (int b = 0; b < 8; ++b) {
    int k = k0 + b;
    tmp.s[b] = (k < K && n < N) ? (short)f2bf(src[(size_t)k*N + n]) : (short)0;
  }
  *reinterpret_cast<bf16x8*>(dst + (size_t)t*8) = tmp.v;
}

// W4' pack for tp1-as-GEMM: step u (0..29), tile j=kk*4+nn; rows k (x3 cols, 63=bias), cols n (0..49 real)
__device__ __forceinline__ void pack_w4n(const float* __restrict__ w4, const float* __restrict__ b4,
                                         uint16_t* __restrict__ dst, int t)
{
  int lane = t & 63;
  int tile = t >> 6;           // 0..239
  int u = tile >> 3, j = tile & 7;
  int kk = j >> 2, nn = j & 3;
  int k0 = kk*32 + ((lane >> 4) << 3);
  int n  = nn*16 + (lane & 15);
  union { short s[8]; bf16x8 v; } tmp;
#pragma unroll
  for (int b = 0; b < 8; ++b) {
    int k = k0 + b;
    float val = 0.f;
    if (n < 50) {
      int cg = (n < 40) ? (u*40 + n) : (1200 + u*10 + (n - 40));
      if (k < 50) val = w4[(size_t)k*1500 + cg];
      else if (k == 63) val = b4[cg];
    }
    tmp.s[b] = (short)f2bf(val);
  }
  *reinterpret_cast<bf16x8*>(dst + (size_t)t*8) = tmp.v;
}

__global__ void prep_kernel(const float* w1a, const float* w2a, const float* w3a, const float* w4a,
                            const float* w1b, const float* w2b, const float* w3b, const float* w4b,
                            const float* b1a, const float* b2a, const float* b3a, const float* b4a,
                            const float* b1b, const float* b2b, const float* b3b, const float* b4b,
                            const float* emb, const int* z, char* ws)
{
  int t = blockIdx.x * 256 + threadIdx.x;
  if      (t < 4096)   pack_mat(w1a, 40, 500, 512,  (uint16_t*)(ws + OFF_W1P1), t);
  else if (t < 36864)  pack_mat(w2a, 500,500, 512,  (uint16_t*)(ws + OFF_W2P1), t - 4096);
  else if (t < 40960)  pack_mat(w3a, 500, 50, 64,   (uint16_t*)(ws + OFF_W3P1), t - 36864);
  else if (t < 45056)  { /* spare */ }
  else if (t < 49152)  pack_mat(w1b, 40, 500, 512,  (uint16_t*)(ws + OFF_W1P2), t - 45056);
  else if (t < 81920)  pack_mat(w2b, 500,500, 512,  (uint16_t*)(ws + OFF_W2P2), t - 49152);
  else if (t < 86016)  pack_mat(w3b, 500, 50, 64,   (uint16_t*)(ws + OFF_W3P2), t - 81920);
  else if (t < 86528)  pack_mat(w4b, 50,  40, 64,   (uint16_t*)(ws + OFF_W4P2), t - 86016);
  else if (t < 90304) {
    int loc = t - 86528;
    const float* src; float* dst; int realN;
    if      (loc < 512)  { src=b1a; dst=(float*)(ws+OFF_B1P1); realN=500; }
    else if (loc < 1024) { src=b2a; dst=(float*)(ws+OFF_B2P1); realN=500;  loc -= 512;  }
    else if (loc < 1088) { src=b3a; dst=(float*)(ws+OFF_B3P1); realN=50;   loc -= 1024; }
    else if (loc < 2624) { src=b4a; dst=(float*)(ws+OFF_B4P1); realN=1500; loc -= 1088; }
    else if (loc < 3136) { src=b1b; dst=(float*)(ws+OFF_B1P2); realN=500;  loc -= 2624; }
    else if (loc < 3648) { src=b2b; dst=(float*)(ws+OFF_B2P2); realN=500;  loc -= 3136; }
    else if (loc < 3712) { src=b3b; dst=(float*)(ws+OFF_B3P2); realN=50;   loc -= 3648; }
    else                 { src=b4b; dst=(float*)(ws+OFF_B4P2); realN=40;   loc -= 3712; }
    dst[loc] = (loc < realN) ? src[loc] : 0.f;
  }
  else if (t < 352448) {
    int i = t - 90304;
    int n = i >> 5, u = i & 31;
    float v = 0.f;
    if (u < 30) v = emb[(size_t)z[n]*30 + u] * INV_SQRT30;
    ((float*)(ws + OFF_HN))[i] = v;
  }
  else if (t < 367808) {
    pack_w4n(w4a, b4a, (uint16_t*)(ws + OFF_W4N1), t - 352448);
  }
}

// ---------------- edge meta ----------------
__global__ void edge_meta(const float* __restrict__ pos, const int* __restrict__ eidx,
                          uint16_t* __restrict__ basis, float* __restrict__ shl)
{
  int e = blockIdx.x * 256 + threadIdx.x;
  if (e >= E_EDGES) return;
  int rn = eidx[e], cn = eidx[E_EDGES + e];
  float ax = pos[rn*3+0] - pos[cn*3+0];
  float ay = pos[rn*3+1] - pos[cn*3+1];
  float az = pos[rn*3+2] - pos[cn*3+2];
  float rr = sqrtf(ax*ax + ay*ay + az*az + 1e-12f);
  float s = SQRT3C * SH0C / rr;
  shl[e*3+0] = ax*s; shl[e*3+1] = ay*s; shl[e*3+2] = az*s;
#pragma unroll
  for (int j = 0; j < 8; ++j) {
    union { short s[8]; bf16x8 v; } tmp;
#pragma unroll
    for (int b = 0; b < 8; ++b) {
      int c = j*8 + b;
      float vv = 0.f;
      if (c < 40) { float t = rr*3.9f - (float)c; vv = __expf(-t*t); }
      tmp.s[b] = (short)f2bf(vv);
    }
    *reinterpret_cast<bf16x8*>(basis + (size_t)e*64 + j*8) = tmp.v;
  }
}

// ---------------- fused MLP: basis[128x64] -> act1 -> act2 (LDS) -> x3[128x64] ----------------
__global__ __launch_bounds__(512, 2)
void fused_mlp(const uint16_t* __restrict__ basis,
               const uint16_t* __restrict__ W1p, const float* __restrict__ b1,
               const uint16_t* __restrict__ W2p, const float* __restrict__ b2,
               const uint16_t* __restrict__ W3p, const float* __restrict__ b3,
               uint16_t* __restrict__ x3)
{
  __shared__ __align__(16) char bas[16384];    // basis tile [128][64] bf16 swizzled
  __shared__ __align__(16) char actb[131072];  // act1 then act2 [128][512] bf16 swizzled

  const int tid = threadIdx.x, lane = tid & 63, wv = tid >> 6;
  const int b = blockIdx.x;
  const int mt = (b & 7) * 160 + (b >> 3);     // bijective for grid 1280
  const int m0 = mt * 128;
  const int r = lane & 15, q = lane >> 4;
  const int rg = wv >> 2, cg = wv & 3;

  const bf16x8* __restrict__ W1v = (const bf16x8*)W1p;
  const bf16x8* __restrict__ W2v = (const bf16x8*)W2p;
  const bf16x8* __restrict__ W3v = (const bf16x8*)W3p;

  // load basis tile (linear dest, pre-swizzled src)
#pragma unroll
  for (int h = 0; h < 2; ++h) {
    int d = tid*16 + h*8192;
    int row = d >> 7;
    int colb = (d & 127) ^ ((row & 7) << 4);
    const char* src = (const char*)basis + (size_t)(m0 + row)*128 + colb;
    __builtin_amdgcn_global_load_lds((const __attribute__((address_space(1))) void*)src,
        (__attribute__((address_space(3))) void*)(&bas[d]), 16, 0, 0);
  }
  asm volatile("s_waitcnt vmcnt(0)" ::: "memory");
  __builtin_amdgcn_s_barrier();

  f32x4 zv = {0.f, 0.f, 0.f, 0.f};

  // ---- stage 1: act1 = swish(basis @ W1 + b1) ----
  {
    f32x4 acc[4][8];
#pragma unroll
    for (int a = 0; a < 4; ++a)
#pragma unroll
      for (int c = 0; c < 8; ++c) acc[a][c] = zv;
#pragma unroll
    for (int ks = 0; ks < 2; ++ks) {
      bf16x8 af[4];
#pragma unroll
      for (int rb = 0; rb < 4; ++rb) {
        int row = rg*64 + rb*16 + r;
        int off = row*128 + ((ks*64 + q*16) ^ ((row & 7) << 4));
        af[rb] = *reinterpret_cast<const bf16x8*>(&bas[off]);
      }
      bf16x8 bfr[8];
#pragma unroll
      for (int nt = 0; nt < 8; ++nt)
        bfr[nt] = W1v[(size_t)((ks*32 + cg*8 + nt)*64 + lane)];
#pragma unroll
      for (int nt = 0; nt < 8; ++nt)
#pragma unroll
        for (int rb = 0; rb < 4; ++rb)
          acc[rb][nt] = __builtin_amdgcn_mfma_f32_16x16x32_bf16(af[rb], bfr[nt], acc[rb][nt], 0, 0, 0);
    }
#pragma unroll
    for (int nt = 0; nt < 8; ++nt) {
      int col = cg*128 + nt*16 + r;
      float bs = b1[col];
#pragma unroll
      for (int rb = 0; rb < 4; ++rb)
#pragma unroll
        for (int i = 0; i < 4; ++i) {
          int row = rg*64 + rb*16 + q*4 + i;
          int off = row*1024 + ((col*2) ^ ((row & 7) << 4));
          *(uint16_t*)(&actb[off]) = f2bf(swishf(acc[rb][nt][i] + bs));
        }
    }
  }
  __syncthreads();

  // ---- stage 2: act2 = swish(act1 @ W2 + b2) ----
  {
    f32x4 acc[4][8];
#pragma unroll
    for (int a = 0; a < 4; ++a)
#pragma unroll
      for (int c = 0; c < 8; ++c) acc[a][c] = zv;
#pragma unroll 2
    for (int ks = 0; ks < 16; ++ks) {
      bf16x8 af[4];
#pragma unroll
      for (int rb = 0; rb < 4; ++rb) {
        int row = rg*64 + rb*16 + r;
        int off = row*1024 + ((ks*64 + q*16) ^ ((row & 7) << 4));
        af[rb] = *reinterpret_cast<const bf16x8*>(&actb[off]);
      }
      bf16x8 bfr[8];
#pragma unroll
      for (int nt = 0; nt < 8; ++nt)
        bfr[nt] = W2v[(size_t)((ks*32 + cg*8 + nt)*64 + lane)];
#pragma unroll
      for (int nt = 0; nt < 8; ++nt)
#pragma unroll
        for (int rb = 0; rb < 4; ++rb)
          acc[rb][nt] = __builtin_amdgcn_mfma_f32_16x16x32_bf16(af[rb], bfr[nt], acc[rb][nt], 0, 0, 0);
    }
    __syncthreads();   // all waves done READING act1
#pragma unroll
    for (int nt = 0; nt < 8; ++nt) {
      int col = cg*128 + nt*16 + r;
      float bs = b2[col];
#pragma unroll
      for (int rb = 0; rb < 4; ++rb)
#pragma unroll
        for (int i = 0; i < 4; ++i) {
          int row = rg*64 + rb*16 + q*4 + i;
          int off = row*1024 + ((col*2) ^ ((row & 7) << 4));
          *(uint16_t*)(&actb[off]) = f2bf(swishf(acc[rb][nt][i] + bs));
        }
    }
  }
  __syncthreads();

  // ---- stage 3: x3 = swish(act2 @ W3 + b3), col63 := 1 ----
  {
    f32x4 acc[4];
#pragma unroll
    for (int a = 0; a < 4; ++a) acc[a] = zv;
#pragma unroll 2
    for (int ks = 0; ks < 16; ++ks) {
      int row = wv*16 + r;
      int off = row*1024 + ((ks*64 + q*16) ^ ((row & 7) << 4));
      bf16x8 a = *reinterpret_cast<const bf16x8*>(&actb[off]);
#pragma unroll
      for (int nt = 0; nt < 4; ++nt) {
        bf16x8 bb = W3v[(size_t)((ks*4 + nt)*64 + lane)];
        acc[nt] = __builtin_amdgcn_mfma_f32_16x16x32_bf16(a, bb, acc[nt], 0, 0, 0);
      }
    }
#pragma unroll
    for (int nt = 0; nt < 4; ++nt) {
      int col = nt*16 + r;
      float bs = b3[col];
#pragma unroll
      for (int i = 0; i < 4; ++i) {
        int row = m0 + wv*16 + q*4 + i;
        float v = swishf(acc[nt][i] + bs);
        if (col == 63) v = 1.f;
        x3[(size_t)row*64 + col] = f2bf(v);
      }
    }
  }
}

// ---------------- TP layer 1 as scaled GEMM ----------------
__global__ __launch_bounds__(512, 4)
void tp1_gemm(const uint16_t* __restrict__ x3, const char* __restrict__ ws,
              const int* __restrict__ eidx, float* __restrict__ agg)
{
  __shared__ __align__(16) uint16_t Wst[2][4096];
  __shared__ float xjs[64*32];
  __shared__ float mbuf[64*64];
  __shared__ float shls[64*3];
  __shared__ int   rowl[64];
  __shared__ int   coll[64];

  const float* hN  = (const float*)(ws + OFF_HN);
  const float* shl = (const float*)(ws + OFF_SHL);
  const char*  W4n = (const char*)(ws + OFF_W4N1);

  const int tid = threadIdx.x, lane = tid & 63, wv = tid >> 6;
  const int e0l = blockIdx.x * 64;
  const int r_ = lane & 15, q_ = lane >> 4;
  const int rowg = wv >> 1, colg = wv & 1;

  if (tid < 64) { rowl[tid] = eidx[e0l + tid]; coll[tid] = eidx[E_EDGES + e0l + tid]; }
  for (int i = tid; i < 192; i += 512) shls[i] = shl[(size_t)e0l*3 + i];
  __syncthreads();
  for (int i = tid; i < 64*32; i += 512) {
    int e = i >> 5, u = i & 31;
    xjs[i] = hN[(size_t)rowl[e]*32 + u];
  }

  bf16x8 a0, a1;
  {
    int row = e0l + rowg*16 + r_;
    const char* base = (const char*)x3 + (size_t)row*128 + q_*16;
    a0 = *reinterpret_cast<const bf16x8*>(base);
    a1 = *reinterpret_cast<const bf16x8*>(base + 64);
  }

  const char* srcW = W4n + ((size_t)(tid >> 6)*64 + lane)*16;
  auto stageW = [&](int buf, int u) {
    __builtin_amdgcn_global_load_lds((const __attribute__((address_space(1))) void*)(srcW + (size_t)u*8192),
        (__attribute__((address_space(3))) void*)(&Wst[buf][(size_t)tid*8]), 16, 0, 0);
  };

  f32x4 zv = {0.f, 0.f, 0.f, 0.f};
  f32x4 accF[2];
  accF[0] = zv; accF[1] = zv;

  stageW(0, 0);
  __syncthreads();

  const char* wb0 = (const char*)&Wst[0][0] + ((size_t)(colg*2)*64 + lane)*16;
  const char* wb1 = (const char*)&Wst[1][0] + ((size_t)(colg*2)*64 + lane)*16;

  int cur = 0;
#pragma unroll 1
  for (int u = 0; u < 30; ++u) {
    if (u + 1 < 30) stageW(cur ^ 1, u + 1);
    const char* wb = cur ? wb1 : wb0;
    bf16x8 b00 = *reinterpret_cast<const bf16x8*>(wb);
    bf16x8 b01 = *reinterpret_cast<const bf16x8*>(wb + 1024);
    bf16x8 b10 = *reinterpret_cast<const bf16x8*>(wb + 4096);
    bf16x8 b11 = *reinterpret_cast<const bf16x8*>(wb + 5120);
    f32x4 t0 = __builtin_amdgcn_mfma_f32_16x16x32_bf16(a0, b00, zv, 0, 0, 0);
    t0 = __builtin_amdgcn_mfma_f32_16x16x32_bf16(a1, b10, t0, 0, 0, 0);
    f32x4 t1 = __builtin_amdgcn_mfma_f32_16x16x32_bf16(a0, b01, zv, 0, 0, 0);
    t1 = __builtin_amdgcn_mfma_f32_16x16x32_bf16(a1, b11, t1, 0, 0, 0);
#pragma unroll
    for (int i = 0; i < 4; ++i) {
      float xv = xjs[(rowg*16 + q_*4 + i)*32 + u];
      accF[0][i] += xv * t0[i];
      accF[1][i] += xv * t1[i];
    }
    if (u + 1 < 30) {
      asm volatile("s_waitcnt vmcnt(0)" ::: "memory");
      __builtin_amdgcn_s_barrier();
      cur ^= 1;
    }
  }

#pragma unroll
  for (int nt = 0; nt < 2; ++nt)
#pragma unroll
    for (int i = 0; i < 4; ++i)
      mbuf[(rowg*16 + q_*4 + i)*64 + colg*32 + nt*16 + r_] = accF[nt][i];
  __syncthreads();

#pragma unroll 1
  for (int i = tid; i < 64*70; i += 512) {
    int e = i/70, c = i - e*70;
    float v;
    if (c < 40) v = mbuf[e*64 + c] * SH0C;
    else { int vv = (c - 40)/3, k = (c - 40) - vv*3; v = mbuf[e*64 + 40 + vv] * shls[e*3 + k]; }
    atomicAdd(&agg[(size_t)coll[e]*70 + c], v);
  }
}

// ---------------- TP layer 2 ----------------
__global__ __launch_bounds__(512, 2)
void tp2_kernel(const uint16_t* __restrict__ x3, const char* __restrict__ ws,
                const int* __restrict__ eidx, float* __restrict__ agg2)
{
  constexpr int P2 = 67;
  __shared__ float wbuf2[64 * P2];
  __shared__ float xjs[64*30];
  __shared__ float xjv[64*30];
  __shared__ float Db[64*10];
  __shared__ float shls[64*3];
  __shared__ int   rowl[64];
  __shared__ int   coll[64];

  const float* h2  = (const float*)(ws + OFF_H2);
  const float* shl = (const float*)(ws + OFF_SHL);
  const float* b4p = (const float*)(ws + OFF_B4P2);
  const bf16x8* __restrict__ bv4 = (const bf16x8*)(ws + OFF_W4P2);

  const int tid = threadIdx.x, lane = tid & 63, wv = tid >> 6;
  const int e0l = blockIdx.x * 64;
  const int r_ = lane & 15, q_ = lane >> 4;

  if (tid < 64) { rowl[tid] = eidx[e0l + tid]; coll[tid] = eidx[E_EDGES + e0l + tid]; }
  for (int i = tid; i < 192; i += 512) shls[i] = shl[(size_t)e0l*3 + i];
  __syncthreads();
  for (int i = tid; i < 64*60; i += 512) {
    int e = i/60, u = i - e*60;
    float v = h2[(size_t)rowl[e]*64 + u];
    if (u < 30) xjs[e*30 + u] = v; else xjv[e*30 + (u - 30)] = v;
  }
  __syncthreads();
  for (int i = tid; i < 640; i += 512) {
    int e = i/10, v = i - e*10;
    float d = 0.f;
#pragma unroll
    for (int m = 0; m < 3; ++m) d += xjv[e*30 + v*3 + m] * shls[e*3 + m];
    Db[i] = d * INV_SQRT3;
  }

  const int rbase = (wv >> 2)*2, nt4 = wv & 3;
  bf16x8 a4[2][2];
#pragma unroll
  for (int kk = 0; kk < 2; ++kk)
#pragma unroll
    for (int rbi = 0; rbi < 2; ++rbi) {
      int row = e0l + (rbase + rbi)*16 + r_;
      a4[kk][rbi] = *reinterpret_cast<const bf16x8*>((const char*)x3 + (size_t)row*128 + kk*64 + q_*16);
    }
  f32x4 acc[2];
  f32x4 zv = {0.f, 0.f, 0.f, 0.f};
  acc[0] = zv; acc[1] = zv;
#pragma unroll
  for (int kk = 0; kk < 2; ++kk) {
    bf16x8 b4 = bv4[(size_t)(kk*4 + nt4)*64 + lane];
#pragma unroll
    for (int rbi = 0; rbi < 2; ++rbi)
      acc[rbi] = __builtin_amdgcn_mfma_f32_16x16x32_bf16(a4[kk][rbi], b4, acc[rbi], 0, 0, 0);
  }
  __syncthreads();
  {
    int cg = nt4*16 + r_;
    float bs = b4p[cg];
#pragma unroll
    for (int rbi = 0; rbi < 2; ++rbi)
#pragma unroll
      for (int i2 = 0; i2 < 4; ++i2) {
        int e = (rbase + rbi)*16 + q_*4 + i2;
        wbuf2[e*P2 + cg] = acc[rbi][i2] + bs;
      }
  }
  __syncthreads();

  if (tid < 64) {
    int e = tid;
    float m = 0.f, m2 = 0.f;
#pragma unroll
    for (int c = 0; c < 30; ++c) m += xjs[e*30 + c] * wbuf2[e*P2 + c];
#pragma unroll
    for (int vv = 0; vv < 10; ++vv) m2 += Db[e*10 + vv] * wbuf2[e*P2 + 30 + vv];
    atomicAdd(&agg2[coll[e]], m * (SH0C * INV_SQRT30) + m2 * INV_SQRT10);
  }
}

// ---------------- node kernels ----------------
__global__ void node_mid(char* ws, const float* __restrict__ si1w)
{
  int nid = blockIdx.x * blockDim.x + threadIdx.x;
  if (nid >= N_NODES) return;
  const float* hN  = (const float*)(ws + OFF_HN)  + (size_t)nid*32;
  const float* agg = (const float*)(ws + OFF_AGG) + (size_t)nid*70;
  float* h2        = (float*)(ws + OFF_H2)        + (size_t)nid*64;

  float hn[30];
#pragma unroll
  for (int u = 0; u < 30; ++u) hn[u] = hN[u];

  float h1[70];
#pragma unroll 1
  for (int v = 0; v < 40; ++v) {
    float s = 0.f;
#pragma unroll
    for (int u = 0; u < 30; ++u) s += hn[u] * si1w[u*40 + v];
    h1[v] = SQ2C * (s + agg[v]);
  }
#pragma unroll
  for (int c = 40; c < 70; ++c) h1[c] = agg[c];

#pragma unroll
  for (int u = 0; u < 30; ++u) h2[u] = swishf(h1[u]);
#pragma unroll
  for (int v = 0; v < 10; ++v) {
    float g = 1.f / (1.f + __expf(-h1[30 + v]));
#pragma unroll
    for (int k = 0; k < 3; ++k) h2[30 + v*3 + k] = h1[40 + v*3 + k] * g;
  }
}

__global__ void node_final(char* ws, const float* __restrict__ si2w, const int* __restrict__ batch)
{
  __shared__ float ls[NGRAPH];
  if (threadIdx.x < NGRAPH) ls[threadIdx.x] = 0.f;
  __syncthreads();
  int nid = blockIdx.x * blockDim.x + threadIdx.x;
  if (nid < N_NODES) {
    const float* h2   = (const float*)(ws + OFF_H2) + (size_t)nid*64;
    const float* agg2 = (const float*)(ws + OFF_AGG2);
    float s2 = 0.f;
#pragma unroll
    for (int u = 0; u < 30; ++u) s2 += h2[u] * si2w[u];
    float val = SQ2C * (s2 * INV_SQRT30 + agg2[nid]);
    atomicAdd(&ls[batch[nid]], val);
  }
  __syncthreads();
  if (threadIdx.x < NGRAPH)
    atomicAdd(((float*)(ws + OFF_GSUM)) + threadIdx.x, ls[threadIdx.x]);
}

__global__ void write_out(const char* ws, float* out)
{
  int g = threadIdx.x;
  if (g < NGRAPH) out[g] = ((const float*)(ws + OFF_GSUM))[g];
}

// ---------------- launch ----------------
extern "C" void kernel_launch(void* const* d_in, const int* in_sizes, int n_in,
                              void* d_out, int out_size, void* d_ws, size_t ws_size,
                              hipStream_t stream)
{
  const float* pos  = (const float*)d_in[0];
  const float* emb  = (const float*)d_in[1];
  const float* si1w = (const float*)d_in[2];
  const float* si2w = (const float*)d_in[3];
  const float* w1a = (const float*)d_in[4];  const float* b1a = (const float*)d_in[5];
  const float* w2a = (const float*)d_in[6];  const float* b2a = (const float*)d_in[7];
  const float* w3a = (const float*)d_in[8];  const float* b3a = (const float*)d_in[9];
  const float* w4a = (const float*)d_in[10]; const float* b4a = (const float*)d_in[11];
  const float* w1b = (const float*)d_in[12]; const float* b1b = (const float*)d_in[13];
  const float* w2b = (const float*)d_in[14]; const float* b2b = (const float*)d_in[15];
  const float* w3b = (const float*)d_in[16]; const float* b3b = (const float*)d_in[17];
  const float* w4b = (const float*)d_in[18]; const float* b4b = (const float*)d_in[19];
  const int* z     = (const int*)d_in[20];
  const int* eidx  = (const int*)d_in[21];
  const int* batch = (const int*)d_in[22];
  char* ws = (char*)d_ws;

  uint16_t* basis = (uint16_t*)(ws + OFF_BAS);
  float*    shl   = (float*)(ws + OFF_SHL);
  uint16_t* x3    = (uint16_t*)(ws + OFF_X3);

  hipMemsetAsync(ws + OFF_AGG, 0, OFF_ZEND - OFF_AGG, stream);

  prep_kernel<<<1437, 256, 0, stream>>>(w1a, w2a, w3a, w4a, w1b, w2b, w3b, w4b,
                                        b1a, b2a, b3a, b4a, b1b, b2b, b3b, b4b,
                                        emb, z, ws);
  edge_meta<<<E_EDGES/256, 256, 0, stream>>>(pos, eidx, basis, shl);

  // ---- layer 1 ----
  fused_mlp<<<E_EDGES/128, 512, 0, stream>>>(basis,
      (const uint16_t*)(ws + OFF_W1P1), (const float*)(ws + OFF_B1P1),
      (const uint16_t*)(ws + OFF_W2P1), (const float*)(ws + OFF_B2P1),
      (const uint16_t*)(ws + OFF_W3P1), (const float*)(ws + OFF_B3P1), x3);
  tp1_gemm<<<E_EDGES/64, 512, 0, stream>>>(x3, ws, eidx, (float*)(ws + OFF_AGG));

  node_mid<<<N_NODES/256, 256, 0, stream>>>(ws, si1w);

  // ---- layer 2 ----
  fused_mlp<<<E_EDGES/128, 512, 0, stream>>>(basis,
      (const uint16_t*)(ws + OFF_W1P2), (const float*)(ws + OFF_B1P2),
      (const uint16_t*)(ws + OFF_W2P2), (const float*)(ws + OFF_B2P2),
      (const uint16_t*)(ws + OFF_W3P2), (const float*)(ws + OFF_B3P2), x3);
  tp2_kernel<<<E_EDGES/64, 512, 0, stream>>>(x3, ws, eidx, (float*)(ws + OFF_AGG2));

  node_final<<<N_NODES/256, 256, 0, stream>>>(ws, si2w, batch);
  write_out<<<1, 64, 0, stream>>>(ws, (float*)d_out);
}

// Round 18
// 671.661 us; speedup vs baseline: 1.5716x; 1.0044x over previous
//
#include <hip/hip_runtime.h>
#include <stdint.h>

typedef __attribute__((ext_vector_type(8))) short bf16x8;
typedef __attribute__((ext_vector_type(4))) float f32x4;

#define N_NODES 8192
#define E_EDGES 163840
#define NGRAPH  32

#define INV_SQRT30 0.18257419f
#define SH0C       0.22360680f   /* 1/sqrt(20) */
#define SQRT3C     1.73205081f
#define INV_SQRT3  0.57735027f
#define INV_SQRT10 0.31622777f
#define SQ2C       0.70710678f

// ---------------- workspace layout (bytes) ----------------
enum : unsigned {
  OFF_W1P1 = 0u,       OFF_W2P1 = 65536u,   OFF_W3P1 = 589824u,  OFF_W4P1 = 655360u,
  OFF_W1P2 = 851968u,  OFF_W2P2 = 917504u,  OFF_W3P2 = 1441792u, OFF_W4P2 = 1507328u,
  OFF_B1P1 = 1515520u, OFF_B2P1 = 1517568u, OFF_B3P1 = 1519616u, OFF_B4P1 = 1519872u,
  OFF_B1P2 = 1526016u, OFF_B2P2 = 1528064u, OFF_B3P2 = 1530112u, OFF_B4P2 = 1530368u,
  OFF_HN   = 1530624u, // [8192][32] f32
  OFF_H2   = 2579200u, // [8192][64] f32
  OFF_AGG  = 4676352u, // [8192][70] f32
  OFF_AGG2 = 6970112u, // [8192] f32
  OFF_GSUM = 7002880u, // [32] f32
  OFF_ZEND = 7003008u,
  OFF_SHL  = 7003136u,  // [E][3] f32
  OFF_BAS  = 8969216u,  // [E][64] bf16 (linear)
  OFF_W4N1 = 29940736u, // 30 x 8 x 1KB
  OFF_X3   = 30186496u  // [E][64] bf16
};

__device__ __forceinline__ uint16_t f2bf(float f){
  union { float f; uint32_t u; } v; v.f = f;
  uint32_t r = v.u + 0x7fffu + ((v.u >> 16) & 1u);
  return (uint16_t)(r >> 16);
}
__device__ __forceinline__ float swishf(float x){ return x / (1.f + __expf(-x)); }

// ---------------- weight pre-pack (f32 src -> bf16 MFMA B-fragment order) ----------------
__device__ __forceinline__ void pack_mat(const float* __restrict__ src, int K, int N, int NP,
                                         uint16_t* __restrict__ dst, int t)
{
  int lane = t & 63;
  int tile = t >> 6;
  int NT = NP >> 4;
  int nn = tile % NT, kk = tile / NT;
  int k0 = kk*32 + ((lane >> 4) << 3);
  int n  = nn*16 + (lane & 15);
  union { short s[8]; bf16x8 v; } tmp;
#pragma unroll
  for (int b = 0; b < 8; ++b) {
    int k = k0 + b;
    tmp.s[b] = (k < K && n < N) ? (short)f2bf(src[(size_t)k*N + n]) : (short)0;
  }
  *reinterpret_cast<bf16x8*>(dst + (size_t)t*8) = tmp.v;
}

// W4' pack for tp1-as-GEMM
__device__ __forceinline__ void pack_w4n(const float* __restrict__ w4, const float* __restrict__ b4,
                                         uint16_t* __restrict__ dst, int t)
{
  int lane = t & 63;
  int tile = t >> 6;           // 0..239
  int u = tile >> 3, j = tile & 7;
  int kk = j >> 2, nn = j & 3;
  int k0 = kk*32 + ((lane >> 4) << 3);
  int n  = nn*16 + (lane & 15);
  union { short s[8]; bf16x8 v; } tmp;
#pragma unroll
  for (int b = 0; b < 8; ++b) {
    int k = k0 + b;
    float val = 0.f;
    if (n < 50) {
      int cg = (n < 40) ? (u*40 + n) : (1200 + u*10 + (n - 40));
      if (k < 50) val = w4[(size_t)k*1500 + cg];
      else if (k == 63) val = b4[cg];
    }
    tmp.s[b] = (short)f2bf(val);
  }
  *reinterpret_cast<bf16x8*>(dst + (size_t)t*8) = tmp.v;
}

__global__ void prep_kernel(const float* w1a, const float* w2a, const float* w3a, const float* w4a,
                            const float* w1b, const float* w2b, const float* w3b, const float* w4b,
                            const float* b1a, const float* b2a, const float* b3a, const float* b4a,
                            const float* b1b, const float* b2b, const float* b3b, const float* b4b,
                            const float* emb, const int* z, char* ws)
{
  int t = blockIdx.x * 256 + threadIdx.x;
  if      (t < 4096)   pack_mat(w1a, 40, 500, 512,  (uint16_t*)(ws + OFF_W1P1), t);
  else if (t < 36864)  pack_mat(w2a, 500,500, 512,  (uint16_t*)(ws + OFF_W2P1), t - 4096);
  else if (t < 40960)  pack_mat(w3a, 500, 50, 64,   (uint16_t*)(ws + OFF_W3P1), t - 36864);
  else if (t < 45056)  { /* spare */ }
  else if (t < 49152)  pack_mat(w1b, 40, 500, 512,  (uint16_t*)(ws + OFF_W1P2), t - 45056);
  else if (t < 81920)  pack_mat(w2b, 500,500, 512,  (uint16_t*)(ws + OFF_W2P2), t - 49152);
  else if (t < 86016)  pack_mat(w3b, 500, 50, 64,   (uint16_t*)(ws + OFF_W3P2), t - 81920);
  else if (t < 86528)  pack_mat(w4b, 50,  40, 64,   (uint16_t*)(ws + OFF_W4P2), t - 86016);
  else if (t < 90304) {
    int loc = t - 86528;
    const float* src; float* dst; int realN;
    if      (loc < 512)  { src=b1a; dst=(float*)(ws+OFF_B1P1); realN=500; }
    else if (loc < 1024) { src=b2a; dst=(float*)(ws+OFF_B2P1); realN=500;  loc -= 512;  }
    else if (loc < 1088) { src=b3a; dst=(float*)(ws+OFF_B3P1); realN=50;   loc -= 1024; }
    else if (loc < 2624) { src=b4a; dst=(float*)(ws+OFF_B4P1); realN=1500; loc -= 1088; }
    else if (loc < 3136) { src=b1b; dst=(float*)(ws+OFF_B1P2); realN=500;  loc -= 2624; }
    else if (loc < 3648) { src=b2b; dst=(float*)(ws+OFF_B2P2); realN=500;  loc -= 3136; }
    else if (loc < 3712) { src=b3b; dst=(float*)(ws+OFF_B3P2); realN=50;   loc -= 3648; }
    else                 { src=b4b; dst=(float*)(ws+OFF_B4P2); realN=40;   loc -= 3712; }
    dst[loc] = (loc < realN) ? src[loc] : 0.f;
  }
  else if (t < 352448) {
    int i = t - 90304;
    int n = i >> 5, u = i & 31;
    float v = 0.f;
    if (u < 30) v = emb[(size_t)z[n]*30 + u] * INV_SQRT30;
    ((float*)(ws + OFF_HN))[i] = v;
  }
  else if (t < 367808) {
    pack_w4n(w4a, b4a, (uint16_t*)(ws + OFF_W4N1), t - 352448);
  }
}

// ---------------- edge meta ----------------
__global__ void edge_meta(const float* __restrict__ pos, const int* __restrict__ eidx,
                          uint16_t* __restrict__ basis, float* __restrict__ shl)
{
  int e = blockIdx.x * 256 + threadIdx.x;
  if (e >= E_EDGES) return;
  int rn = eidx[e], cn = eidx[E_EDGES + e];
  float ax = pos[rn*3+0] - pos[cn*3+0];
  float ay = pos[rn*3+1] - pos[cn*3+1];
  float az = pos[rn*3+2] - pos[cn*3+2];
  float rr = sqrtf(ax*ax + ay*ay + az*az + 1e-12f);
  float s = SQRT3C * SH0C / rr;
  shl[e*3+0] = ax*s; shl[e*3+1] = ay*s; shl[e*3+2] = az*s;
#pragma unroll
  for (int j = 0; j < 8; ++j) {
    union { short s[8]; bf16x8 v; } tmp;
#pragma unroll
    for (int b = 0; b < 8; ++b) {
      int c = j*8 + b;
      float vv = 0.f;
      if (c < 40) { float t = rr*3.9f - (float)c; vv = __expf(-t*t); }
      tmp.s[b] = (short)f2bf(vv);
    }
    *reinterpret_cast<bf16x8*>(basis + (size_t)e*64 + j*8) = tmp.v;
  }
}

// ---------------- fused MLP, 64-row tiles, 2 blocks/CU ----------------
__global__ __launch_bounds__(512, 4)
void fused_mlp(const uint16_t* __restrict__ basis,
               const uint16_t* __restrict__ W1p, const float* __restrict__ b1,
               const uint16_t* __restrict__ W2p, const float* __restrict__ b2,
               const uint16_t* __restrict__ W3p, const float* __restrict__ b3,
               uint16_t* __restrict__ x3)
{
  __shared__ __align__(16) char actb[65536];   // [64][512] bf16, XOR-swizzled

  const int tid = threadIdx.x, lane = tid & 63, wv = tid >> 6;
  const int m0 = blockIdx.x * 64;
  const int r = lane & 15, q = lane >> 4;

  const bf16x8* __restrict__ W1v = (const bf16x8*)W1p;
  const bf16x8* __restrict__ W2v = (const bf16x8*)W2p;
  const bf16x8* __restrict__ W3v = (const bf16x8*)W3p;

  f32x4 zv = {0.f, 0.f, 0.f, 0.f};

  // ---- stage 1: act1 = swish(basis @ W1 + b1); A direct from global ----
  {
    f32x4 acc[4][4];
#pragma unroll
    for (int a = 0; a < 4; ++a)
#pragma unroll
      for (int c = 0; c < 4; ++c) acc[a][c] = zv;
#pragma unroll
    for (int ks = 0; ks < 2; ++ks) {
      bf16x8 af[4];
#pragma unroll
      for (int rb = 0; rb < 4; ++rb) {
        int row = m0 + rb*16 + r;
        af[rb] = *reinterpret_cast<const bf16x8*>((const char*)basis + (size_t)row*128 + ks*64 + q*16);
      }
      bf16x8 bfr[4];
#pragma unroll
      for (int nt = 0; nt < 4; ++nt)
        bfr[nt] = W1v[(size_t)((ks*32 + wv*4 + nt)*64 + lane)];
#pragma unroll
      for (int nt = 0; nt < 4; ++nt)
#pragma unroll
        for (int rb = 0; rb < 4; ++rb)
          acc[rb][nt] = __builtin_amdgcn_mfma_f32_16x16x32_bf16(af[rb], bfr[nt], acc[rb][nt], 0, 0, 0);
    }
#pragma unroll
    for (int nt = 0; nt < 4; ++nt) {
      int col = wv*64 + nt*16 + r;
      float bs = b1[col];
#pragma unroll
      for (int rb = 0; rb < 4; ++rb)
#pragma unroll
        for (int i = 0; i < 4; ++i) {
          int row = rb*16 + q*4 + i;
          int off = row*1024 + ((col*2) ^ ((row & 7) << 4));
          *(uint16_t*)(&actb[off]) = f2bf(swishf(acc[rb][nt][i] + bs));
        }
    }
  }
  __syncthreads();

  // ---- stage 2: act2 = swish(act1 @ W2 + b2) ----
  {
    f32x4 acc[4][4];
#pragma unroll
    for (int a = 0; a < 4; ++a)
#pragma unroll
      for (int c = 0; c < 4; ++c) acc[a][c] = zv;
#pragma unroll 2
    for (int ks = 0; ks < 16; ++ks) {
      bf16x8 af[4];
#pragma unroll
      for (int rb = 0; rb < 4; ++rb) {
        int row = rb*16 + r;
        int off = row*1024 + ((ks*64 + q*16) ^ ((row & 7) << 4));
        af[rb] = *reinterpret_cast<const bf16x8*>(&actb[off]);
      }
      bf16x8 bfr[4];
#pragma unroll
      for (int nt = 0; nt < 4; ++nt)
        bfr[nt] = W2v[(size_t)((ks*32 + wv*4 + nt)*64 + lane)];
#pragma unroll
      for (int nt = 0; nt < 4; ++nt)
#pragma unroll
        for (int rb = 0; rb < 4; ++rb)
          acc[rb][nt] = __builtin_amdgcn_mfma_f32_16x16x32_bf16(af[rb], bfr[nt], acc[rb][nt], 0, 0, 0);
    }
    __syncthreads();   // all waves done READING act1
#pragma unroll
    for (int nt = 0; nt < 4; ++nt) {
      int col = wv*64 + nt*16 + r;
      float bs = b2[col];
#pragma unroll
      for (int rb = 0; rb < 4; ++rb)
#pragma unroll
        for (int i = 0; i < 4; ++i) {
          int row = rb*16 + q*4 + i;
          int off = row*1024 + ((col*2) ^ ((row & 7) << 4));
          *(uint16_t*)(&actb[off]) = f2bf(swishf(acc[rb][nt][i] + bs));
        }
    }
  }
  __syncthreads();

  // ---- stage 3: x3 = swish(act2 @ W3 + b3), col63 := 1; 2 tiles/wave ----
  {
    const int rb3 = wv >> 1, ntp = (wv & 1)*2;
    f32x4 acc[2];
    acc[0] = zv; acc[1] = zv;
#pragma unroll 2
    for (int ks = 0; ks < 16; ++ks) {
      int row = rb3*16 + r;
      int off = row*1024 + ((ks*64 + q*16) ^ ((row & 7) << 4));
      bf16x8 a = *reinterpret_cast<const bf16x8*>(&actb[off]);
#pragma unroll
      for (int j = 0; j < 2; ++j) {
        bf16x8 bb = W3v[(size_t)((ks*4 + ntp + j)*64 + lane)];
        acc[j] = __builtin_amdgcn_mfma_f32_16x16x32_bf16(a, bb, acc[j], 0, 0, 0);
      }
    }
#pragma unroll
    for (int j = 0; j < 2; ++j) {
      int col = (ntp + j)*16 + r;
      float bs = b3[col];
#pragma unroll
      for (int i = 0; i < 4; ++i) {
        int row = m0 + rb3*16 + q*4 + i;
        float v = swishf(acc[j][i] + bs);
        if (col == 63) v = 1.f;
        x3[(size_t)row*64 + col] = f2bf(v);
      }
    }
  }
}

// ---------------- TP layer 1 as scaled GEMM ----------------
__global__ __launch_bounds__(512, 4)
void tp1_gemm(const uint16_t* __restrict__ x3, const char* __restrict__ ws,
              const int* __restrict__ eidx, float* __restrict__ agg)
{
  __shared__ __align__(16) uint16_t Wst[2][4096];
  __shared__ float xjs[64*32];
  __shared__ float mbuf[64*64];
  __shared__ float shls[64*3];
  __shared__ int   rowl[64];
  __shared__ int   coll[64];

  const float* hN  = (const float*)(ws + OFF_HN);
  const float* shl = (const float*)(ws + OFF_SHL);
  const char*  W4n = (const char*)(ws + OFF_W4N1);

  const int tid = threadIdx.x, lane = tid & 63, wv = tid >> 6;
  const int e0l = blockIdx.x * 64;
  const int r_ = lane & 15, q_ = lane >> 4;
  const int rowg = wv >> 1, colg = wv & 1;

  if (tid < 64) { rowl[tid] = eidx[e0l + tid]; coll[tid] = eidx[E_EDGES + e0l + tid]; }
  for (int i = tid; i < 192; i += 512) shls[i] = shl[(size_t)e0l*3 + i];
  __syncthreads();
  for (int i = tid; i < 64*32; i += 512) {
    int e = i >> 5, u = i & 31;
    xjs[i] = hN[(size_t)rowl[e]*32 + u];
  }

  bf16x8 a0, a1;
  {
    int row = e0l + rowg*16 + r_;
    const char* base = (const char*)x3 + (size_t)row*128 + q_*16;
    a0 = *reinterpret_cast<const bf16x8*>(base);
    a1 = *reinterpret_cast<const bf16x8*>(base + 64);
  }

  const char* srcW = W4n + ((size_t)(tid >> 6)*64 + lane)*16;
  auto stageW = [&](int buf, int u) {
    __builtin_amdgcn_global_load_lds((const __attribute__((address_space(1))) void*)(srcW + (size_t)u*8192),
        (__attribute__((address_space(3))) void*)(&Wst[buf][(size_t)tid*8]), 16, 0, 0);
  };

  f32x4 zv = {0.f, 0.f, 0.f, 0.f};
  f32x4 accF[2];
  accF[0] = zv; accF[1] = zv;

  stageW(0, 0);
  __syncthreads();

  const char* wb0 = (const char*)&Wst[0][0] + ((size_t)(colg*2)*64 + lane)*16;
  const char* wb1 = (const char*)&Wst[1][0] + ((size_t)(colg*2)*64 + lane)*16;

  int cur = 0;
#pragma unroll 1
  for (int u = 0; u < 30; ++u) {
    if (u + 1 < 30) stageW(cur ^ 1, u + 1);
    const char* wb = cur ? wb1 : wb0;
    bf16x8 b00 = *reinterpret_cast<const bf16x8*>(wb);
    bf16x8 b01 = *reinterpret_cast<const bf16x8*>(wb + 1024);
    bf16x8 b10 = *reinterpret_cast<const bf16x8*>(wb + 4096);
    bf16x8 b11 = *reinterpret_cast<const bf16x8*>(wb + 5120);
    f32x4 t0 = __builtin_amdgcn_mfma_f32_16x16x32_bf16(a0, b00, zv, 0, 0, 0);
    t0 = __builtin_amdgcn_mfma_f32_16x16x32_bf16(a1, b10, t0, 0, 0, 0);
    f32x4 t1 = __builtin_amdgcn_mfma_f32_16x16x32_bf16(a0, b01, zv, 0, 0, 0);
    t1 = __builtin_amdgcn_mfma_f32_16x16x32_bf16(a1, b11, t1, 0, 0, 0);
#pragma unroll
    for (int i = 0; i < 4; ++i) {
      float xv = xjs[(rowg*16 + q_*4 + i)*32 + u];
      accF[0][i] += xv * t0[i];
      accF[1][i] += xv * t1[i];
    }
    if (u + 1 < 30) {
      asm volatile("s_waitcnt vmcnt(0)" ::: "memory");
      __builtin_amdgcn_s_barrier();
      cur ^= 1;
    }
  }

#pragma unroll
  for (int nt = 0; nt < 2; ++nt)
#pragma unroll
    for (int i = 0; i < 4; ++i)
      mbuf[(rowg*16 + q_*4 + i)*64 + colg*32 + nt*16 + r_] = accF[nt][i];
  __syncthreads();

#pragma unroll 1
  for (int i = tid; i < 64*70; i += 512) {
    int e = i/70, c = i - e*70;
    float v;
    if (c < 40) v = mbuf[e*64 + c] * SH0C;
    else { int vv = (c - 40)/3, k = (c - 40) - vv*3; v = mbuf[e*64 + 40 + vv] * shls[e*3 + k]; }
    atomicAdd(&agg[(size_t)coll[e]*70 + c], v);
  }
}

// ---------------- TP layer 2 ----------------
__global__ __launch_bounds__(512, 2)
void tp2_kernel(const uint16_t* __restrict__ x3, const char* __restrict__ ws,
                const int* __restrict__ eidx, float* __restrict__ agg2)
{
  constexpr int P2 = 67;
  __shared__ float wbuf2[64 * P2];
  __shared__ float xjs[64*30];
  __shared__ float xjv[64*30];
  __shared__ float Db[64*10];
  __shared__ float shls[64*3];
  __shared__ int   rowl[64];
  __shared__ int   coll[64];

  const float* h2  = (const float*)(ws + OFF_H2);
  const float* shl = (const float*)(ws + OFF_SHL);
  const float* b4p = (const float*)(ws + OFF_B4P2);
  const bf16x8* __restrict__ bv4 = (const bf16x8*)(ws + OFF_W4P2);

  const int tid = threadIdx.x, lane = tid & 63, wv = tid >> 6;
  const int e0l = blockIdx.x * 64;
  const int r_ = lane & 15, q_ = lane >> 4;

  if (tid < 64) { rowl[tid] = eidx[e0l + tid]; coll[tid] = eidx[E_EDGES + e0l + tid]; }
  for (int i = tid; i < 192; i += 512) shls[i] = shl[(size_t)e0l*3 + i];
  __syncthreads();
  for (int i = tid; i < 64*60; i += 512) {
    int e = i/60, u = i - e*60;
    float v = h2[(size_t)rowl[e]*64 + u];
    if (u < 30) xjs[e*30 + u] = v; else xjv[e*30 + (u - 30)] = v;
  }
  __syncthreads();
  for (int i = tid; i < 640; i += 512) {
    int e = i/10, v = i - e*10;
    float d = 0.f;
#pragma unroll
    for (int m = 0; m < 3; ++m) d += xjv[e*30 + v*3 + m] * shls[e*3 + m];
    Db[i] = d * INV_SQRT3;
  }

  const int rbase = (wv >> 2)*2, nt4 = wv & 3;
  bf16x8 a4[2][2];
#pragma unroll
  for (int kk = 0; kk < 2; ++kk)
#pragma unroll
    for (int rbi = 0; rbi < 2; ++rbi) {
      int row = e0l + (rbase + rbi)*16 + r_;
      a4[kk][rbi] = *reinterpret_cast<const bf16x8*>((const char*)x3 + (size_t)row*128 + kk*64 + q_*16);
    }
  f32x4 acc[2];
  f32x4 zv = {0.f, 0.f, 0.f, 0.f};
  acc[0] = zv; acc[1] = zv;
#pragma unroll
  for (int kk = 0; kk < 2; ++kk) {
    bf16x8 b4 = bv4[(size_t)(kk*4 + nt4)*64 + lane];
#pragma unroll
    for (int rbi = 0; rbi < 2; ++rbi)
      acc[rbi] = __builtin_amdgcn_mfma_f32_16x16x32_bf16(a4[kk][rbi], b4, acc[rbi], 0, 0, 0);
  }
  __syncthreads();
  {
    int cg = nt4*16 + r_;
    float bs = b4p[cg];
#pragma unroll
    for (int rbi = 0; rbi < 2; ++rbi)
#pragma unroll
      for (int i2 = 0; i2 < 4; ++i2) {
        int e = (rbase + rbi)*16 + q_*4 + i2;
        wbuf2[e*P2 + cg] = acc[rbi][i2] + bs;
      }
  }
  __syncthreads();

  if (tid < 64) {
    int e = tid;
    float m = 0.f, m2 = 0.f;
#pragma unroll
    for (int c = 0; c < 30; ++c) m += xjs[e*30 + c] * wbuf2[e*P2 + c];
#pragma unroll
    for (int vv = 0; vv < 10; ++vv) m2 += Db[e*10 + vv] * wbuf2[e*P2 + 30 + vv];
    atomicAdd(&agg2[coll[e]], m * (SH0C * INV_SQRT30) + m2 * INV_SQRT10);
  }
}

// ---------------- node kernels ----------------
__global__ void node_mid(char* ws, const float* __restrict__ si1w)
{
  int nid = blockIdx.x * blockDim.x + threadIdx.x;
  if (nid >= N_NODES) return;
  const float* hN  = (const float*)(ws + OFF_HN)  + (size_t)nid*32;
  const float* agg = (const float*)(ws + OFF_AGG) + (size_t)nid*70;
  float* h2        = (float*)(ws + OFF_H2)        + (size_t)nid*64;

  float hn[30];
#pragma unroll
  for (int u = 0; u < 30; ++u) hn[u] = hN[u];

  float h1[70];
#pragma unroll 1
  for (int v = 0; v < 40; ++v) {
    float s = 0.f;
#pragma unroll
    for (int u = 0; u < 30; ++u) s += hn[u] * si1w[u*40 + v];
    h1[v] = SQ2C * (s + agg[v]);
  }
#pragma unroll
  for (int c = 40; c < 70; ++c) h1[c] = agg[c];

#pragma unroll
  for (int u = 0; u < 30; ++u) h2[u] = swishf(h1[u]);
#pragma unroll
  for (int v = 0; v < 10; ++v) {
    float g = 1.f / (1.f + __expf(-h1[30 + v]));
#pragma unroll
    for (int k = 0; k < 3; ++k) h2[30 + v*3 + k] = h1[40 + v*3 + k] * g;
  }
}

__global__ void node_final(char* ws, const float* __restrict__ si2w, const int* __restrict__ batch)
{
  __shared__ float ls[NGRAPH];
  if (threadIdx.x < NGRAPH) ls[threadIdx.x] = 0.f;
  __syncthreads();
  int nid = blockIdx.x * blockDim.x + threadIdx.x;
  if (nid < N_NODES) {
    const float* h2   = (const float*)(ws + OFF_H2) + (size_t)nid*64;
    const float* agg2 = (const float*)(ws + OFF_AGG2);
    float s2 = 0.f;
#pragma unroll
    for (int u = 0; u < 30; ++u) s2 += h2[u] * si2w[u];
    float val = SQ2C * (s2 * INV_SQRT30 + agg2[nid]);
    atomicAdd(&ls[batch[nid]], val);
  }
  __syncthreads();
  if (threadIdx.x < NGRAPH)
    atomicAdd(((float*)(ws + OFF_GSUM)) + threadIdx.x, ls[threadIdx.x]);
}

__global__ void write_out(const char* ws, float* out)
{
  int g = threadIdx.x;
  if (g < NGRAPH) out[g] = ((const float*)(ws + OFF_GSUM))[g];
}

// ---------------- launch ----------------
extern "C" void kernel_launch(void* const* d_in, const int* in_sizes, int n_in,
                              void* d_out, int out_size, void* d_ws, size_t ws_size,
                              hipStream_t stream)
{
  const float* pos  = (const float*)d_in[0];
  const float* emb  = (const float*)d_in[1];
  const float* si1w = (const float*)d_in[2];
  const float* si2w = (const float*)d_in[3];
  const float* w1a = (const float*)d_in[4];  const float* b1a = (const float*)d_in[5];
  const float* w2a = (const float*)d_in[6];  const float* b2a = (const float*)d_in[7];
  const float* w3a = (const float*)d_in[8];  const float* b3a = (const float*)d_in[9];
  const float* w4a = (const float*)d_in[10]; const float* b4a = (const float*)d_in[11];
  const float* w1b = (const float*)d_in[12]; const float* b1b = (const float*)d_in[13];
  const float* w2b = (const float*)d_in[14]; const float* b2b = (const float*)d_in[15];
  const float* w3b = (const float*)d_in[16]; const float* b3b = (const float*)d_in[17];
  const float* w4b = (const float*)d_in[18]; const float* b4b = (const float*)d_in[19];
  const int* z     = (const int*)d_in[20];
  const int* eidx  = (const int*)d_in[21];
  const int* batch = (const int*)d_in[22];
  char* ws = (char*)d_ws;

  uint16_t* basis = (uint16_t*)(ws + OFF_BAS);
  float*    shl   = (float*)(ws + OFF_SHL);
  uint16_t* x3    = (uint16_t*)(ws + OFF_X3);

  hipMemsetAsync(ws + OFF_AGG, 0, OFF_ZEND - OFF_AGG, stream);

  prep_kernel<<<1437, 256, 0, stream>>>(w1a, w2a, w3a, w4a, w1b, w2b, w3b, w4b,
                                        b1a, b2a, b3a, b4a, b1b, b2b, b3b, b4b,
                                        emb, z, ws);
  edge_meta<<<E_EDGES/256, 256, 0, stream>>>(pos, eidx, basis, shl);

  // ---- layer 1 ----
  fused_mlp<<<E_EDGES/64, 512, 0, stream>>>(basis,
      (const uint16_t*)(ws + OFF_W1P1), (const float*)(ws + OFF_B1P1),
      (const uint16_t*)(ws + OFF_W2P1), (const float*)(ws + OFF_B2P1),
      (const uint16_t*)(ws + OFF_W3P1), (const float*)(ws + OFF_B3P1), x3);
  tp1_gemm<<<E_EDGES/64, 512, 0, stream>>>(x3, ws, eidx, (float*)(ws + OFF_AGG));

  node_mid<<<N_NODES/256, 256, 0, stream>>>(ws, si1w);

  // ---- layer 2 ----
  fused_mlp<<<E_EDGES/64, 512, 0, stream>>>(basis,
      (const uint16_t*)(ws + OFF_W1P2), (const float*)(ws + OFF_B1P2),
      (const uint16_t*)(ws + OFF_W2P2), (const float*)(ws + OFF_B2P2),
      (const uint16_t*)(ws + OFF_W3P2), (const float*)(ws + OFF_B3P2), x3);
  tp2_kernel<<<E_EDGES/64, 512, 0, stream>>>(x3, ws, eidx, (float*)(ws + OFF_AGG2));

  node_final<<<N_NODES/256, 256, 0, stream>>>(ws, si2w, batch);
  write_out<<<1, 64, 0, stream>>>(ws, (float*)d_out);
}

// Round 19
// 588.091 us; speedup vs baseline: 1.7949x; 1.1421x over previous
//
#include <hip/hip_runtime.h>
#include <stdint.h>

typedef __attribute__((ext_vector_type(8))) short bf16x8;
typedef __attribute__((ext_vector_type(4))) float f32x4;

#define N_NODES 8192
#define E_EDGES 163840
#define NGRAPH  32

#define INV_SQRT30 0.18257419f
#define SH0C       0.22360680f   /* 1/sqrt(20) */
#define SQRT3C     1.73205081f
#define INV_SQRT3  0.57735027f
#define INV_SQRT10 0.31622777f
#define SQ2C       0.70710678f

// ---------------- workspace layout (bytes) ----------------
enum : unsigned {
  OFF_W1P1 = 0u,       OFF_W2P1 = 65536u,   OFF_W3P1 = 589824u,  OFF_W4P1 = 655360u,
  OFF_W1P2 = 851968u,  OFF_W2P2 = 917504u,  OFF_W3P2 = 1441792u, OFF_W4P2 = 1507328u,
  OFF_B1P1 = 1515520u, OFF_B2P1 = 1517568u, OFF_B3P1 = 1519616u, OFF_B4P1 = 1519872u,
  OFF_B1P2 = 1526016u, OFF_B2P2 = 1528064u, OFF_B3P2 = 1530112u, OFF_B4P2 = 1530368u,
  OFF_HN   = 1530624u, // [8192][32] f32
  OFF_H2   = 2579200u, // [8192][64] f32
  OFF_AGG  = 4676352u, // [8192][70] f32
  OFF_AGG2 = 6970112u, // [8192] f32
  OFF_GSUM = 7002880u, // [32] f32
  OFF_ZEND = 7003008u,
  OFF_SHL  = 7003136u,  // [E][3] f32
  OFF_BAS  = 8969216u,  // [E][64] bf16 (linear)
  OFF_W4N1 = 29940736u, // 30 x 8 x 1KB
  OFF_X3   = 30186496u  // [E][64] bf16
};

__device__ __forceinline__ uint16_t f2bf(float f){
  union { float f; uint32_t u; } v; v.f = f;
  uint32_t r = v.u + 0x7fffu + ((v.u >> 16) & 1u);
  return (uint16_t)(r >> 16);
}
__device__ __forceinline__ float swishf(float x){ return x / (1.f + __expf(-x)); }

// ---------------- weight pre-pack (f32 src -> bf16 MFMA B-fragment order) ----------------
__device__ __forceinline__ void pack_mat(const float* __restrict__ src, int K, int N, int NP,
                                         uint16_t* __restrict__ dst, int t)
{
  int lane = t & 63;
  int tile = t >> 6;
  int NT = NP >> 4;
  int nn = tile % NT, kk = tile / NT;
  int k0 = kk*32 + ((lane >> 4) << 3);
  int n  = nn*16 + (lane & 15);
  union { short s[8]; bf16x8 v; } tmp;
#pragma unroll
  for (int b = 0; b < 8; ++b) {
    int k = k0 + b;
    tmp.s[b] = (k < K && n < N) ? (short)f2bf(src[(size_t)k*N + n]) : (short)0;
  }
  *reinterpret_cast<bf16x8*>(dst + (size_t)t*8) = tmp.v;
}

// W4' pack for tp1-as-GEMM
__device__ __forceinline__ void pack_w4n(const float* __restrict__ w4, const float* __restrict__ b4,
                                         uint16_t* __restrict__ dst, int t)
{
  int lane = t & 63;
  int tile = t >> 6;           // 0..239
  int u = tile >> 3, j = tile & 7;
  int kk = j >> 2, nn = j & 3;
  int k0 = kk*32 + ((lane >> 4) << 3);
  int n  = nn*16 + (lane & 15);
  union { short s[8]; bf16x8 v; } tmp;
#pragma unroll
  for (int b = 0; b < 8; ++b) {
    int k = k0 + b;
    float val = 0.f;
    if (n < 50) {
      int cg = (n < 40) ? (u*40 + n) : (1200 + u*10 + (n - 40));
      if (k < 50) val = w4[(size_t)k*1500 + cg];
      else if (k == 63) val = b4[cg];
    }
    tmp.s[b] = (short)f2bf(val);
  }
  *reinterpret_cast<bf16x8*>(dst + (size_t)t*8) = tmp.v;
}

__global__ void prep_kernel(const float* w1a, const float* w2a, const float* w3a, const float* w4a,
                            const float* w1b, const float* w2b, const float* w3b, const float* w4b,
                            const float* b1a, const float* b2a, const float* b3a, const float* b4a,
                            const float* b1b, const float* b2b, const float* b3b, const float* b4b,
                            const float* emb, const int* z, char* ws)
{
  int t = blockIdx.x * 256 + threadIdx.x;
  if      (t < 4096)   pack_mat(w1a, 40, 500, 512,  (uint16_t*)(ws + OFF_W1P1), t);
  else if (t < 36864)  pack_mat(w2a, 500,500, 512,  (uint16_t*)(ws + OFF_W2P1), t - 4096);
  else if (t < 40960)  pack_mat(w3a, 500, 50, 64,   (uint16_t*)(ws + OFF_W3P1), t - 36864);
  else if (t < 45056)  { /* spare */ }
  else if (t < 49152)  pack_mat(w1b, 40, 500, 512,  (uint16_t*)(ws + OFF_W1P2), t - 45056);
  else if (t < 81920)  pack_mat(w2b, 500,500, 512,  (uint16_t*)(ws + OFF_W2P2), t - 49152);
  else if (t < 86016)  pack_mat(w3b, 500, 50, 64,   (uint16_t*)(ws + OFF_W3P2), t - 81920);
  else if (t < 86528)  pack_mat(w4b, 50,  40, 64,   (uint16_t*)(ws + OFF_W4P2), t - 86016);
  else if (t < 90304) {
    int loc = t - 86528;
    const float* src; float* dst; int realN;
    if      (loc < 512)  { src=b1a; dst=(float*)(ws+OFF_B1P1); realN=500; }
    else if (loc < 1024) { src=b2a; dst=(float*)(ws+OFF_B2P1); realN=500;  loc -= 512;  }
    else if (loc < 1088) { src=b3a; dst=(float*)(ws+OFF_B3P1); realN=50;   loc -= 1024; }
    else if (loc < 2624) { src=b4a; dst=(float*)(ws+OFF_B4P1); realN=1500; loc -= 1088; }
    else if (loc < 3136) { src=b1b; dst=(float*)(ws+OFF_B1P2); realN=500;  loc -= 2624; }
    else if (loc < 3648) { src=b2b; dst=(float*)(ws+OFF_B2P2); realN=500;  loc -= 3136; }
    else if (loc < 3712) { src=b3b; dst=(float*)(ws+OFF_B3P2); realN=50;   loc -= 3648; }
    else                 { src=b4b; dst=(float*)(ws+OFF_B4P2); realN=40;   loc -= 3712; }
    dst[loc] = (loc < realN) ? src[loc] : 0.f;
  }
  else if (t < 352448) {
    int i = t - 90304;
    int n = i >> 5, u = i & 31;
    float v = 0.f;
    if (u < 30) v = emb[(size_t)z[n]*30 + u] * INV_SQRT30;
    ((float*)(ws + OFF_HN))[i] = v;
  }
  else if (t < 367808) {
    pack_w4n(w4a, b4a, (uint16_t*)(ws + OFF_W4N1), t - 352448);
  }
}

// ---------------- edge meta ----------------
__global__ void edge_meta(const float* __restrict__ pos, const int* __restrict__ eidx,
                          uint16_t* __restrict__ basis, float* __restrict__ shl)
{
  int e = blockIdx.x * 256 + threadIdx.x;
  if (e >= E_EDGES) return;
  int rn = eidx[e], cn = eidx[E_EDGES + e];
  float ax = pos[rn*3+0] - pos[cn*3+0];
  float ay = pos[rn*3+1] - pos[cn*3+1];
  float az = pos[rn*3+2] - pos[cn*3+2];
  float rr = sqrtf(ax*ax + ay*ay + az*az + 1e-12f);
  float s = SQRT3C * SH0C / rr;
  shl[e*3+0] = ax*s; shl[e*3+1] = ay*s; shl[e*3+2] = az*s;
#pragma unroll
  for (int j = 0; j < 8; ++j) {
    union { short s[8]; bf16x8 v; } tmp;
#pragma unroll
    for (int b = 0; b < 8; ++b) {
      int c = j*8 + b;
      float vv = 0.f;
      if (c < 40) { float t = rr*3.9f - (float)c; vv = __expf(-t*t); }
      tmp.s[b] = (short)f2bf(vv);
    }
    *reinterpret_cast<bf16x8*>(basis + (size_t)e*64 + j*8) = tmp.v;
  }
}

// ---------------- fused MLP, 64-row tiles, 256-reg budget (no spill) ----------------
__global__ __launch_bounds__(512, 2)
void fused_mlp(const uint16_t* __restrict__ basis,
               const uint16_t* __restrict__ W1p, const float* __restrict__ b1,
               const uint16_t* __restrict__ W2p, const float* __restrict__ b2,
               const uint16_t* __restrict__ W3p, const float* __restrict__ b3,
               uint16_t* __restrict__ x3)
{
  __shared__ __align__(16) char actb[65536];   // [64][512] bf16, XOR-swizzled

  const int tid = threadIdx.x, lane = tid & 63, wv = tid >> 6;
  const int m0 = blockIdx.x * 64;
  const int r = lane & 15, q = lane >> 4;

  const bf16x8* __restrict__ W1v = (const bf16x8*)W1p;
  const bf16x8* __restrict__ W2v = (const bf16x8*)W2p;
  const bf16x8* __restrict__ W3v = (const bf16x8*)W3p;

  f32x4 zv = {0.f, 0.f, 0.f, 0.f};

  // ---- stage 1: act1 = swish(basis @ W1 + b1); A direct from global ----
  {
    f32x4 acc[4][4];
#pragma unroll
    for (int a = 0; a < 4; ++a)
#pragma unroll
      for (int c = 0; c < 4; ++c) acc[a][c] = zv;
#pragma unroll
    for (int ks = 0; ks < 2; ++ks) {
      bf16x8 af[4];
#pragma unroll
      for (int rb = 0; rb < 4; ++rb) {
        int row = m0 + rb*16 + r;
        af[rb] = *reinterpret_cast<const bf16x8*>((const char*)basis + (size_t)row*128 + ks*64 + q*16);
      }
#pragma unroll
      for (int c2 = 0; c2 < 2; ++c2) {
        bf16x8 bfr[2];
#pragma unroll
        for (int j = 0; j < 2; ++j)
          bfr[j] = W1v[(size_t)((ks*32 + wv*4 + c2*2 + j)*64 + lane)];
#pragma unroll
        for (int j = 0; j < 2; ++j)
#pragma unroll
          for (int rb = 0; rb < 4; ++rb)
            acc[rb][c2*2 + j] = __builtin_amdgcn_mfma_f32_16x16x32_bf16(af[rb], bfr[j], acc[rb][c2*2 + j], 0, 0, 0);
      }
    }
#pragma unroll
    for (int nt = 0; nt < 4; ++nt) {
      int col = wv*64 + nt*16 + r;
      float bs = b1[col];
#pragma unroll
      for (int rb = 0; rb < 4; ++rb)
#pragma unroll
        for (int i = 0; i < 4; ++i) {
          int row = rb*16 + q*4 + i;
          int off = row*1024 + ((col*2) ^ ((row & 7) << 4));
          *(uint16_t*)(&actb[off]) = f2bf(swishf(acc[rb][nt][i] + bs));
        }
    }
  }
  __syncthreads();

  // ---- stage 2: act2 = swish(act1 @ W2 + b2) ----
  {
    f32x4 acc[4][4];
#pragma unroll
    for (int a = 0; a < 4; ++a)
#pragma unroll
      for (int c = 0; c < 4; ++c) acc[a][c] = zv;
#pragma unroll 1
    for (int ks = 0; ks < 16; ++ks) {
      bf16x8 af[4];
#pragma unroll
      for (int rb = 0; rb < 4; ++rb) {
        int row = rb*16 + r;
        int off = row*1024 + ((ks*64 + q*16) ^ ((row & 7) << 4));
        af[rb] = *reinterpret_cast<const bf16x8*>(&actb[off]);
      }
#pragma unroll
      for (int c2 = 0; c2 < 2; ++c2) {
        bf16x8 bfr[2];
#pragma unroll
        for (int j = 0; j < 2; ++j)
          bfr[j] = W2v[(size_t)((ks*32 + wv*4 + c2*2 + j)*64 + lane)];
#pragma unroll
        for (int j = 0; j < 2; ++j)
#pragma unroll
          for (int rb = 0; rb < 4; ++rb)
            acc[rb][c2*2 + j] = __builtin_amdgcn_mfma_f32_16x16x32_bf16(af[rb], bfr[j], acc[rb][c2*2 + j], 0, 0, 0);
      }
    }
    __syncthreads();   // all waves done READING act1
#pragma unroll
    for (int nt = 0; nt < 4; ++nt) {
      int col = wv*64 + nt*16 + r;
      float bs = b2[col];
#pragma unroll
      for (int rb = 0; rb < 4; ++rb)
#pragma unroll
        for (int i = 0; i < 4; ++i) {
          int row = rb*16 + q*4 + i;
          int off = row*1024 + ((col*2) ^ ((row & 7) << 4));
          *(uint16_t*)(&actb[off]) = f2bf(swishf(acc[rb][nt][i] + bs));
        }
    }
  }
  __syncthreads();

  // ---- stage 3: x3 = swish(act2 @ W3 + b3), col63 := 1; 2 tiles/wave ----
  {
    const int rb3 = wv >> 1, ntp = (wv & 1)*2;
    f32x4 acc[2];
    acc[0] = zv; acc[1] = zv;
#pragma unroll 2
    for (int ks = 0; ks < 16; ++ks) {
      int row = rb3*16 + r;
      int off = row*1024 + ((ks*64 + q*16) ^ ((row & 7) << 4));
      bf16x8 a = *reinterpret_cast<const bf16x8*>(&actb[off]);
#pragma unroll
      for (int j = 0; j < 2; ++j) {
        bf16x8 bb = W3v[(size_t)((ks*4 + ntp + j)*64 + lane)];
        acc[j] = __builtin_amdgcn_mfma_f32_16x16x32_bf16(a, bb, acc[j], 0, 0, 0);
      }
    }
#pragma unroll
    for (int j = 0; j < 2; ++j) {
      int col = (ntp + j)*16 + r;
      float bs = b3[col];
#pragma unroll
      for (int i = 0; i < 4; ++i) {
        int row = m0 + rb3*16 + q*4 + i;
        float v = swishf(acc[j][i] + bs);
        if (col == 63) v = 1.f;
        x3[(size_t)row*64 + col] = f2bf(v);
      }
    }
  }
}

// ---------------- TP layer 1 as scaled GEMM ----------------
__global__ __launch_bounds__(512, 4)
void tp1_gemm(const uint16_t* __restrict__ x3, const char* __restrict__ ws,
              const int* __restrict__ eidx, float* __restrict__ agg)
{
  __shared__ __align__(16) uint16_t Wst[2][4096];
  __shared__ float xjs[64*32];
  __shared__ float mbuf[64*64];
  __shared__ float shls[64*3];
  __shared__ int   rowl[64];
  __shared__ int   coll[64];

  const float* hN  = (const float*)(ws + OFF_HN);
  const float* shl = (const float*)(ws + OFF_SHL);
  const char*  W4n = (const char*)(ws + OFF_W4N1);

  const int tid = threadIdx.x, lane = tid & 63, wv = tid >> 6;
  const int e0l = blockIdx.x * 64;
  const int r_ = lane & 15, q_ = lane >> 4;
  const int rowg = wv >> 1, colg = wv & 1;

  if (tid < 64) { rowl[tid] = eidx[e0l + tid]; coll[tid] = eidx[E_EDGES + e0l + tid]; }
  for (int i = tid; i < 192; i += 512) shls[i] = shl[(size_t)e0l*3 + i];
  __syncthreads();
  for (int i = tid; i < 64*32; i += 512) {
    int e = i >> 5, u = i & 31;
    xjs[i] = hN[(size_t)rowl[e]*32 + u];
  }

  bf16x8 a0, a1;
  {
    int row = e0l + rowg*16 + r_;
    const char* base = (const char*)x3 + (size_t)row*128 + q_*16;
    a0 = *reinterpret_cast<const bf16x8*>(base);
    a1 = *reinterpret_cast<const bf16x8*>(base + 64);
  }

  const char* srcW = W4n + ((size_t)(tid >> 6)*64 + lane)*16;
  auto stageW = [&](int buf, int u) {
    __builtin_amdgcn_global_load_lds((const __attribute__((address_space(1))) void*)(srcW + (size_t)u*8192),
        (__attribute__((address_space(3))) void*)(&Wst[buf][(size_t)tid*8]), 16, 0, 0);
  };

  f32x4 zv = {0.f, 0.f, 0.f, 0.f};
  f32x4 accF[2];
  accF[0] = zv; accF[1] = zv;

  stageW(0, 0);
  __syncthreads();

  const char* wb0 = (const char*)&Wst[0][0] + ((size_t)(colg*2)*64 + lane)*16;
  const char* wb1 = (const char*)&Wst[1][0] + ((size_t)(colg*2)*64 + lane)*16;

  int cur = 0;
#pragma unroll 1
  for (int u = 0; u < 30; ++u) {
    if (u + 1 < 30) stageW(cur ^ 1, u + 1);
    const char* wb = cur ? wb1 : wb0;
    bf16x8 b00 = *reinterpret_cast<const bf16x8*>(wb);
    bf16x8 b01 = *reinterpret_cast<const bf16x8*>(wb + 1024);
    bf16x8 b10 = *reinterpret_cast<const bf16x8*>(wb + 4096);
    bf16x8 b11 = *reinterpret_cast<const bf16x8*>(wb + 5120);
    f32x4 t0 = __builtin_amdgcn_mfma_f32_16x16x32_bf16(a0, b00, zv, 0, 0, 0);
    t0 = __builtin_amdgcn_mfma_f32_16x16x32_bf16(a1, b10, t0, 0, 0, 0);
    f32x4 t1 = __builtin_amdgcn_mfma_f32_16x16x32_bf16(a0, b01, zv, 0, 0, 0);
    t1 = __builtin_amdgcn_mfma_f32_16x16x32_bf16(a1, b11, t1, 0, 0, 0);
#pragma unroll
    for (int i = 0; i < 4; ++i) {
      float xv = xjs[(rowg*16 + q_*4 + i)*32 + u];
      accF[0][i] += xv * t0[i];
      accF[1][i] += xv * t1[i];
    }
    if (u + 1 < 30) {
      asm volatile("s_waitcnt vmcnt(0)" ::: "memory");
      __builtin_amdgcn_s_barrier();
      cur ^= 1;
    }
  }

#pragma unroll
  for (int nt = 0; nt < 2; ++nt)
#pragma unroll
    for (int i = 0; i < 4; ++i)
      mbuf[(rowg*16 + q_*4 + i)*64 + colg*32 + nt*16 + r_] = accF[nt][i];
  __syncthreads();

#pragma unroll 1
  for (int i = tid; i < 64*70; i += 512) {
    int e = i/70, c = i - e*70;
    float v;
    if (c < 40) v = mbuf[e*64 + c] * SH0C;
    else { int vv = (c - 40)/3, k = (c - 40) - vv*3; v = mbuf[e*64 + 40 + vv] * shls[e*3 + k]; }
    atomicAdd(&agg[(size_t)coll[e]*70 + c], v);
  }
}

// ---------------- TP layer 2 ----------------
__global__ __launch_bounds__(512, 2)
void tp2_kernel(const uint16_t* __restrict__ x3, const char* __restrict__ ws,
                const int* __restrict__ eidx, float* __restrict__ agg2)
{
  constexpr int P2 = 67;
  __shared__ float wbuf2[64 * P2];
  __shared__ float xjs[64*30];
  __shared__ float xjv[64*30];
  __shared__ float Db[64*10];
  __shared__ float shls[64*3];
  __shared__ int   rowl[64];
  __shared__ int   coll[64];

  const float* h2  = (const float*)(ws + OFF_H2);
  const float* shl = (const float*)(ws + OFF_SHL);
  const float* b4p = (const float*)(ws + OFF_B4P2);
  const bf16x8* __restrict__ bv4 = (const bf16x8*)(ws + OFF_W4P2);

  const int tid = threadIdx.x, lane = tid & 63, wv = tid >> 6;
  const int e0l = blockIdx.x * 64;
  const int r_ = lane & 15, q_ = lane >> 4;

  if (tid < 64) { rowl[tid] = eidx[e0l + tid]; coll[tid] = eidx[E_EDGES + e0l + tid]; }
  for (int i = tid; i < 192; i += 512) shls[i] = shl[(size_t)e0l*3 + i];
  __syncthreads();
  for (int i = tid; i < 64*60; i += 512) {
    int e = i/60, u = i - e*60;
    float v = h2[(size_t)rowl[e]*64 + u];
    if (u < 30) xjs[e*30 + u] = v; else xjv[e*30 + (u - 30)] = v;
  }
  __syncthreads();
  for (int i = tid; i < 640; i += 512) {
    int e = i/10, v = i - e*10;
    float d = 0.f;
#pragma unroll
    for (int m = 0; m < 3; ++m) d += xjv[e*30 + v*3 + m] * shls[e*3 + m];
    Db[i] = d * INV_SQRT3;
  }

  const int rbase = (wv >> 2)*2, nt4 = wv & 3;
  bf16x8 a4[2][2];
#pragma unroll
  for (int kk = 0; kk < 2; ++kk)
#pragma unroll
    for (int rbi = 0; rbi < 2; ++rbi) {
      int row = e0l + (rbase + rbi)*16 + r_;
      a4[kk][rbi] = *reinterpret_cast<const bf16x8*>((const char*)x3 + (size_t)row*128 + kk*64 + q_*16);
    }
  f32x4 acc[2];
  f32x4 zv = {0.f, 0.f, 0.f, 0.f};
  acc[0] = zv; acc[1] = zv;
#pragma unroll
  for (int kk = 0; kk < 2; ++kk) {
    bf16x8 b4 = bv4[(size_t)(kk*4 + nt4)*64 + lane];
#pragma unroll
    for (int rbi = 0; rbi < 2; ++rbi)
      acc[rbi] = __builtin_amdgcn_mfma_f32_16x16x32_bf16(a4[kk][rbi], b4, acc[rbi], 0, 0, 0);
  }
  __syncthreads();
  {
    int cg = nt4*16 + r_;
    float bs = b4p[cg];
#pragma unroll
    for (int rbi = 0; rbi < 2; ++rbi)
#pragma unroll
      for (int i2 = 0; i2 < 4; ++i2) {
        int e = (rbase + rbi)*16 + q_*4 + i2;
        wbuf2[e*P2 + cg] = acc[rbi][i2] + bs;
      }
  }
  __syncthreads();

  if (tid < 64) {
    int e = tid;
    float m = 0.f, m2 = 0.f;
#pragma unroll
    for (int c = 0; c < 30; ++c) m += xjs[e*30 + c] * wbuf2[e*P2 + c];
#pragma unroll
    for (int vv = 0; vv < 10; ++vv) m2 += Db[e*10 + vv] * wbuf2[e*P2 + 30 + vv];
    atomicAdd(&agg2[coll[e]], m * (SH0C * INV_SQRT30) + m2 * INV_SQRT10);
  }
}

// ---------------- node kernels ----------------
__global__ void node_mid(char* ws, const float* __restrict__ si1w)
{
  int nid = blockIdx.x * blockDim.x + threadIdx.x;
  if (nid >= N_NODES) return;
  const float* hN  = (const float*)(ws + OFF_HN)  + (size_t)nid*32;
  const float* agg = (const float*)(ws + OFF_AGG) + (size_t)nid*70;
  float* h2        = (float*)(ws + OFF_H2)        + (size_t)nid*64;

  float hn[30];
#pragma unroll
  for (int u = 0; u < 30; ++u) hn[u] = hN[u];

  float h1[70];
#pragma unroll 1
  for (int v = 0; v < 40; ++v) {
    float s = 0.f;
#pragma unroll
    for (int u = 0; u < 30; ++u) s += hn[u] * si1w[u*40 + v];
    h1[v] = SQ2C * (s + agg[v]);
  }
#pragma unroll
  for (int c = 40; c < 70; ++c) h1[c] = agg[c];

#pragma unroll
  for (int u = 0; u < 30; ++u) h2[u] = swishf(h1[u]);
#pragma unroll
  for (int v = 0; v < 10; ++v) {
    float g = 1.f / (1.f + __expf(-h1[30 + v]));
#pragma unroll
    for (int k = 0; k < 3; ++k) h2[30 + v*3 + k] = h1[40 + v*3 + k] * g;
  }
}

__global__ void node_final(char* ws, const float* __restrict__ si2w, const int* __restrict__ batch)
{
  __shared__ float ls[NGRAPH];
  if (threadIdx.x < NGRAPH) ls[threadIdx.x] = 0.f;
  __syncthreads();
  int nid = blockIdx.x * blockDim.x + threadIdx.x;
  if (nid < N_NODES) {
    const float* h2   = (const float*)(ws + OFF_H2) + (size_t)nid*64;
    const float* agg2 = (const float*)(ws + OFF_AGG2);
    float s2 = 0.f;
#pragma unroll
    for (int u = 0; u < 30; ++u) s2 += h2[u] * si2w[u];
    float val = SQ2C * (s2 * INV_SQRT30 + agg2[nid]);
    atomicAdd(&ls[batch[nid]], val);
  }
  __syncthreads();
  if (threadIdx.x < NGRAPH)
    atomicAdd(((float*)(ws + OFF_GSUM)) + threadIdx.x, ls[threadIdx.x]);
}

__global__ void write_out(const char* ws, float* out)
{
  int g = threadIdx.x;
  if (g < NGRAPH) out[g] = ((const float*)(ws + OFF_GSUM))[g];
}

// ---------------- launch ----------------
extern "C" void kernel_launch(void* const* d_in, const int* in_sizes, int n_in,
                              void* d_out, int out_size, void* d_ws, size_t ws_size,
                              hipStream_t stream)
{
  const float* pos  = (const float*)d_in[0];
  const float* emb  = (const float*)d_in[1];
  const float* si1w = (const float*)d_in[2];
  const float* si2w = (const float*)d_in[3];
  const float* w1a = (const float*)d_in[4];  const float* b1a = (const float*)d_in[5];
  const float* w2a = (const float*)d_in[6];  const float* b2a = (const float*)d_in[7];
  const float* w3a = (const float*)d_in[8];  const float* b3a = (const float*)d_in[9];
  const float* w4a = (const float*)d_in[10]; const float* b4a = (const float*)d_in[11];
  const float* w1b = (const float*)d_in[12]; const float* b1b = (const float*)d_in[13];
  const float* w2b = (const float*)d_in[14]; const float* b2b = (const float*)d_in[15];
  const float* w3b = (const float*)d_in[16]; const float* b3b = (const float*)d_in[17];
  const float* w4b = (const float*)d_in[18]; const float* b4b = (const float*)d_in[19];
  const int* z     = (const int*)d_in[20];
  const int* eidx  = (const int*)d_in[21];
  const int* batch = (const int*)d_in[22];
  char* ws = (char*)d_ws;

  uint16_t* basis = (uint16_t*)(ws + OFF_BAS);
  float*    shl   = (float*)(ws + OFF_SHL);
  uint16_t* x3    = (uint16_t*)(ws + OFF_X3);

  hipMemsetAsync(ws + OFF_AGG, 0, OFF_ZEND - OFF_AGG, stream);

  prep_kernel<<<1437, 256, 0, stream>>>(w1a, w2a, w3a, w4a, w1b, w2b, w3b, w4b,
                                        b1a, b2a, b3a, b4a, b1b, b2b, b3b, b4b,
                                        emb, z, ws);
  edge_meta<<<E_EDGES/256, 256, 0, stream>>>(pos, eidx, basis, shl);

  // ---- layer 1 ----
  fused_mlp<<<E_EDGES/64, 512, 0, stream>>>(basis,
      (const uint16_t*)(ws + OFF_W1P1), (const float*)(ws + OFF_B1P1),
      (const uint16_t*)(ws + OFF_W2P1), (const float*)(ws + OFF_B2P1),
      (const uint16_t*)(ws + OFF_W3P1), (const float*)(ws + OFF_B3P1), x3);
  tp1_gemm<<<E_EDGES/64, 512, 0, stream>>>(x3, ws, eidx, (float*)(ws + OFF_AGG));

  node_mid<<<N_NODES/256, 256, 0, stream>>>(ws, si1w);

  // ---- layer 2 ----
  fused_mlp<<<E_EDGES/64, 512, 0, stream>>>(basis,
      (const uint16_t*)(ws + OFF_W1P2), (const float*)(ws + OFF_B1P2),
      (const uint16_t*)(ws + OFF_W2P2), (const float*)(ws + OFF_B2P2),
      (const uint16_t*)(ws + OFF_W3P2), (const float*)(ws + OFF_B3P2), x3);
  tp2_kernel<<<E_EDGES/64, 512, 0, stream>>>(x3, ws, eidx, (float*)(ws + OFF_AGG2));

  node_final<<<N_NODES/256, 256, 0, stream>>>(ws, si2w, batch);
  write_out<<<1, 64, 0, stream>>>(ws, (float*)d_out);
}